// Round 5
// baseline (459.979 us; speedup 1.0000x reference)
//
#include <hip/hip_runtime.h>
#include <cmath>

#define NB 8
#define NN 4096
#define DF 128
#define NH 4
#define NJ 32
#define NK 128
#define NTOT (NB*NN)          // 32768
#define ETOT 524288           // 8 * 4096 * 16
#define BPB (NH*NB*NJ)        // 1024
#define DHID 256
#define NCLS 16

#define FP_SCALE 4194304.0    // 2^22 fixed-point for deterministic score scatter
#define FP_INV   (1.0/4194304.0)

typedef short bf16x8 __attribute__((ext_vector_type(8)));
typedef float f32x4  __attribute__((ext_vector_type(4)));

__device__ __forceinline__ unsigned short f2bf(float f) {
    unsigned u = __float_as_uint(f);
    unsigned r = (u + 0x7FFFu + ((u >> 16) & 1u)) >> 16;   // RNE
    return (unsigned short)r;
}

// sortable u64 key: ascending k64 == (descending score, ascending idx) — matches argsort(-s) stable
__device__ __forceinline__ unsigned long long make_key(float sc, int p) {
    unsigned u = __float_as_uint(sc);
    unsigned s = u ^ ((unsigned)((int)u >> 31) | 0x80000000u);   // ascending-float map
    return ((unsigned long long)(s ^ 0xFFFFFFFFu) << 12) | (unsigned)p;
}

// ---------------- init ----------------
__global__ void k0_init(int* deg_i, int* iscore, int* cnt, int* fill, int* fill2) {
    int t = blockIdx.x * blockDim.x + threadIdx.x;
    if (t < NTOT * NH) iscore[t] = 0;
    if (t < NTOT) { deg_i[t] = 0; fill2[t] = 0; }
    if (t < BPB) { cnt[t] = 0; fill[t] = 0; }
}

// in-degree (int, exact, deterministic)
__global__ void k1_deg(const int* __restrict__ ei, int* deg_i) {
    int e = blockIdx.x * blockDim.x + threadIdx.x;
    if (e >= ETOT) return;
    atomicAdd(&deg_i[ei[ETOT + e]], 1);
}

// rdeg = 1/sqrt(1+indeg)
__global__ void k1b_rdeg(const int* __restrict__ deg_i, float* __restrict__ rdeg) {
    int t = blockIdx.x * blockDim.x + threadIdx.x;
    if (t >= NTOT) return;
    rdeg[t] = 1.0f / sqrtf((float)(1 + deg_i[t]));
}

// W1T_bf[n][k] = bf16(W1[k][n])   (256x256, coalesced reads)
__global__ void kw_w1t(const float* __restrict__ W1, unsigned short* __restrict__ w1t) {
    int t = blockIdx.x * 256 + threadIdx.x;     // 65536
    int k = t >> 8, n = t & 255;
    w1t[n * 256 + k] = f2bf(W1[k * DHID + n]);
}

// scores_pre = x_flat @ W_rank  (double accum: minimizes sort-flip risk)
__global__ void k2_scores(const float* __restrict__ x, const float* __restrict__ wr,
                          float* __restrict__ scores_pre) {
    int t = blockIdx.x * blockDim.x + threadIdx.x;
    if (t >= NTOT * NH) return;
    int g = t >> 2, hh = t & 3;
    const float* xr = x + (size_t)g * DF;
    double acc = 0.0;
    for (int d0 = 0; d0 < DF; ++d0) acc += (double)xr[d0] * (double)wr[d0 * NH + hh];
    scores_pre[t] = (float)acc;
}

// score scatter: fixed-point int atomics -> deterministic (f32 weight; quantization dominates)
__global__ void k3_scatter_scores(const int* __restrict__ ei, const float* __restrict__ rdeg,
                                  const float* __restrict__ scores_pre, int* iscore) {
    int t = blockIdx.x * blockDim.x + threadIdx.x;
    if (t >= ETOT * NH) return;
    int e = t >> 2, hh = t & 3;
    int s = ei[e], d = ei[ETOT + e];
    float w = rdeg[s] * rdeg[d];
    double term = (double)(w * scores_pre[s * NH + hh]);
    atomicAdd(&iscore[d * NH + hh], __double2int_rn(term * FP_SCALE));
}

// exclusive scan of in-degrees over 32768 nodes (single block)
__global__ __launch_bounds__(1024) void k3b_scan(const int* __restrict__ deg_i, int* nbase) {
    __shared__ int part[1024];
    int t = threadIdx.x;
    int base0 = t * 32;
    int local[32];
    int s = 0;
#pragma unroll
    for (int i = 0; i < 32; ++i) { local[i] = s; s += deg_i[base0 + i]; }
    part[t] = s;
    __syncthreads();
    for (int off = 1; off < 1024; off <<= 1) {
        int v = (t >= off) ? part[t - off] : 0;
        __syncthreads();
        part[t] += v;
        __syncthreads();
    }
    int myoff = (t == 0) ? 0 : part[t - 1];
#pragma unroll
    for (int i = 0; i < 32; ++i) nbase[base0 + i] = myoff + local[i];
    if (t == 1023) nbase[NTOT] = part[1023];
}

// fill dst-CSR: csr_src[nbase[d] + slot] = s
__global__ void k3c_fill_csr(const int* __restrict__ ei, const int* __restrict__ nbase,
                             int* fill2, int* __restrict__ csr_src) {
    int e = blockIdx.x * blockDim.x + threadIdx.x;
    if (e >= ETOT) return;
    int s = ei[e], d = ei[ETOT + e];
    int slot = atomicAdd(&fill2[d], 1);
    csr_src[nbase[d] + slot] = s;
}

// gather: xapp[g,:] = x[g,:]/deg + sum_{s in N(g)} rdeg[g]*rdeg[s]*x[s,:]
__global__ __launch_bounds__(256) void k4_gather(const int* __restrict__ csr_src,
                                                 const int* __restrict__ nbase,
                                                 const float* __restrict__ rdeg,
                                                 const float* __restrict__ x,
                                                 float* __restrict__ xapp) {
    int wv = (blockIdx.x * 256 + threadIdx.x) >> 6;   // node id
    if (wv >= NTOT) return;
    int lane = threadIdx.x & 63;
    float rd = rdeg[wv];
    float acc0 = x[(size_t)wv * DF + lane] * rd * rd;
    float acc1 = x[(size_t)wv * DF + 64 + lane] * rd * rd;
    int t0 = nbase[wv], t1 = nbase[wv + 1];
    for (int t = t0; t < t1; ++t) {
        int s = csr_src[t];
        float w = rd * rdeg[s];
        acc0 += w * x[(size_t)s * DF + lane];
        acc1 += w * x[(size_t)s * DF + 64 + lane];
    }
    xapp[(size_t)wv * DF + lane] = acc0;
    xapp[(size_t)wv * DF + 64 + lane] = acc1;
}

// G = concat(x, xapp) @ W1 via bf16 MFMA.  M=32768, N=256, K=256.
__global__ __launch_bounds__(256) void kg_mfma(const float* __restrict__ x,
                                               const float* __restrict__ xapp,
                                               const unsigned short* __restrict__ w1t,
                                               float* __restrict__ G) {
    __shared__ __align__(16) unsigned short As[128 * 64];  // [row][k] swizzled
    __shared__ __align__(16) unsigned short Bs[128 * 64];  // [n][k]   swizzled
    int bid = blockIdx.x;
    int m0 = (bid >> 1) * 128, n0 = (bid & 1) * 128;
    int tid = threadIdx.x, lane = tid & 63, wid = tid >> 6;
    int wr = wid >> 1, wc = wid & 1;
    f32x4 acc[4][4];
#pragma unroll
    for (int mi = 0; mi < 4; ++mi)
#pragma unroll
        for (int ni = 0; ni < 4; ++ni) acc[mi][ni] = f32x4{0.f, 0.f, 0.f, 0.f};

    for (int kk = 0; kk < 4; ++kk) {
        int k0 = kk * 64;
        const float* Asrc = (k0 < 128) ? x : xapp;
        int kbase = k0 & 127;
#pragma unroll
        for (int i = 0; i < 4; ++i) {
            int gi = tid + i * 256;
            int r = gi >> 3, c = gi & 7;
            int csrc = c ^ (r & 7);
            const float* sp = Asrc + (size_t)(m0 + r) * DF + kbase + csrc * 8;
            float4 lo = *(const float4*)sp;
            float4 hi = *(const float4*)(sp + 4);
            unsigned short u[8] = {f2bf(lo.x), f2bf(lo.y), f2bf(lo.z), f2bf(lo.w),
                                   f2bf(hi.x), f2bf(hi.y), f2bf(hi.z), f2bf(hi.w)};
            *(bf16x8*)&As[r * 64 + c * 8] = *(bf16x8*)u;
        }
#pragma unroll
        for (int i = 0; i < 4; ++i) {
            int gi = tid + i * 256;
            int r = gi >> 3, c = gi & 7;
            int csrc = c ^ (r & 7);
            *(bf16x8*)&Bs[r * 64 + c * 8] =
                *(const bf16x8*)(w1t + (size_t)(n0 + r) * 256 + k0 + csrc * 8);
        }
        __syncthreads();
#pragma unroll
        for (int ks = 0; ks < 2; ++ks) {
            bf16x8 af[4], bfr[4];
#pragma unroll
            for (int mi = 0; mi < 4; ++mi) {
                int r = wr * 64 + mi * 16 + (lane & 15);
                int gl = ks * 4 + (lane >> 4);
                af[mi] = *(const bf16x8*)&As[r * 64 + (gl ^ (r & 7)) * 8];
            }
#pragma unroll
            for (int ni = 0; ni < 4; ++ni) {
                int r = wc * 64 + ni * 16 + (lane & 15);
                int gl = ks * 4 + (lane >> 4);
                bfr[ni] = *(const bf16x8*)&Bs[r * 64 + (gl ^ (r & 7)) * 8];
            }
#pragma unroll
            for (int mi = 0; mi < 4; ++mi)
#pragma unroll
                for (int ni = 0; ni < 4; ++ni)
                    acc[mi][ni] = __builtin_amdgcn_mfma_f32_16x16x32_bf16(
                        af[mi], bfr[ni], acc[mi][ni], 0, 0, 0);
        }
        __syncthreads();
    }
#pragma unroll
    for (int mi = 0; mi < 4; ++mi) {
        int rbase = m0 + wr * 64 + mi * 16 + (lane >> 4) * 4;
#pragma unroll
        for (int ni = 0; ni < 4; ++ni) {
            int col = n0 + wc * 64 + ni * 16 + (lane & 15);
#pragma unroll
            for (int j = 0; j < 4; ++j)
                G[(size_t)(rbase + j) * DHID + col] = acc[mi][ni][j];
        }
    }
}

// sort phase A: 512-element chunk bitonic sort on packed u64 keys (one block per chunk)
__global__ __launch_bounds__(256) void k5a_chunk(const float* __restrict__ scores_pre,
                                                 const int* __restrict__ iscore,
                                                 const int* __restrict__ deg_i,
                                                 unsigned long long* __restrict__ sorted64) {
    __shared__ unsigned long long sk[512];
    int blk = blockIdx.x;            // seg*8 + chunk
    int seg = blk >> 3, chunk = blk & 7;
    int b = seg >> 2, hh = seg & 3;
    int tid = threadIdx.x;
    for (int i = tid; i < 512; i += 256) {
        int p = chunk * 512 + i;
        int g = b * NN + p;
        float dg = (float)(1 + deg_i[g]);
        float sc = scores_pre[g * NH + hh] / dg + (float)((double)iscore[g * NH + hh] * FP_INV);
        sk[i] = make_key(sc, p);
    }
    __syncthreads();
    for (int size = 2; size <= 512; size <<= 1) {
        for (int stride = size >> 1; stride > 0; stride >>= 1) {
            for (int p = tid; p < 512; p += 256) {
                int q = p ^ stride;
                if (q > p) {
                    unsigned long long kp = sk[p], kq = sk[q];
                    bool before_qp = (kq < kp);
                    bool asc = ((p & size) == 0);
                    if (asc ? before_qp : !before_qp) { sk[p] = kq; sk[q] = kp; }
                }
            }
            __syncthreads();
        }
    }
    for (int i = tid; i < 512; i += 256)
        sorted64[seg * NN + chunk * 512 + i] = sk[i];
}

// sort phase B: rank via binary searches over the other 7 sorted chunks (no barriers)
__global__ __launch_bounds__(256) void k5b_rank(const unsigned long long* __restrict__ sorted64,
                                                int* __restrict__ order, int* __restrict__ pos,
                                                float* __restrict__ val) {
    int t = blockIdx.x * 256 + threadIdx.x;      // 131072
    int seg = t >> 12, i = t & 4095;
    int chunk = i >> 9, slot = i & 511;
    const unsigned long long* segp = sorted64 + (size_t)seg * NN;
    unsigned long long k = segp[chunk * 512 + slot];
    int rank = slot;
#pragma unroll
    for (int c = 0; c < 8; ++c) {
        if (c == chunk) continue;
        const unsigned long long* cp = segp + c * 512;
        int lo = 0, hi = 512;
        while (lo < hi) { int mid = (lo + hi) >> 1; lo = (cp[mid] < k) ? mid + 1 : lo; hi = (cp[mid] < k) ? hi : mid; }
        rank += lo;
    }
    int p = (int)(k & 4095u);
    pos[seg * NN + p] = rank;
    order[seg * NN + rank] = p;
    unsigned s = (unsigned)(k >> 12) ^ 0xFFFFFFFFu;
    unsigned u = s ^ (((int)s >= 0) ? 0xFFFFFFFFu : 0x80000000u);
    float sc = __uint_as_float(u);
    val[seg * NN + rank] = 1.0f / (1.0f + expf(-sc));
}

// sort phase C: tgt = rank of order[p] by node-id within its 128-block
__global__ __launch_bounds__(128) void k5c_tgt(const int* __restrict__ order,
                                               int* __restrict__ tgt) {
    __shared__ int o[128];
    int base = blockIdx.x * 128;     // = seg*4096 + j*128
    int tid = threadIdx.x;
    o[tid] = order[base + tid];
    __syncthreads();
    int me = o[tid];
    int r = 0;
#pragma unroll 16
    for (int s2 = 0; s2 < 128; ++s2) r += (o[s2] < me) ? 1 : 0;
    tgt[base + tid] = r;
}

// classify each (edge, head): compute block-pair id + slots, count per block, emit record
__global__ void k6_classify(const int* __restrict__ ei, const int* __restrict__ pos,
                            int* cnt, unsigned* __restrict__ rec) {
    int t = blockIdx.x * blockDim.x + threadIdx.x;
    if (t >= ETOT * NH) return;
    int e = t >> 2, hh = t & 3;
    int s = ei[e], d = ei[ETOT + e];
    int b = s >> 12, sl = s & 4095, dl = d & 4095;
    int ph = (b << 2) | hh;
    int ps = pos[ph * NN + sl], pd = pos[ph * NN + dl];
    unsigned r = 0xFFFFFFFFu;
    if ((ps >> 7) == (pd >> 7)) {
        int bpid = ((hh * NB + b) * NJ) + (ps >> 7);
        atomicAdd(&cnt[bpid], 1);
        r = ((unsigned)bpid << 14) | ((unsigned)(ps & 127) << 7) | (unsigned)(pd & 127);
    }
    rec[t] = r;
}

__global__ __launch_bounds__(1024) void k7_scan(const int* __restrict__ cnt, int* base) {
    __shared__ int sh[BPB];
    int t = threadIdx.x;
    sh[t] = cnt[t];
    __syncthreads();
    for (int off = 1; off < BPB; off <<= 1) {
        int v = (t >= off) ? sh[t - off] : 0;
        __syncthreads();
        sh[t] += v;
        __syncthreads();
    }
    base[t + 1] = sh[t];
    if (t == 0) base[0] = 0;
}

__global__ void k8_fill(const unsigned* __restrict__ rec, const int* __restrict__ base,
                        int* fill, unsigned* elist) {
    int t = blockIdx.x * blockDim.x + threadIdx.x;
    if (t >= ETOT * NH) return;
    unsigned r = rec[t];
    if (r == 0xFFFFFFFFu) return;
    int bpid = r >> 14;
    int ss = (r >> 7) & 127, sd = r & 127;
    int k2 = atomicAdd(&fill[bpid], 1);
    elist[base[bpid] + k2] = (unsigned)(ss | (sd << 16));
}

// per-block: bucket edges by row-chunk once, then per-chunk LDS-atomic AXPY accumulation.
// Hh rows = relu(sum_edges coef * G[node_d,:]), mean over 128 rows, @ W_out
__global__ __launch_bounds__(256) void k9_block(const float* __restrict__ G,
                                                const int* __restrict__ order,
                                                const float* __restrict__ val,
                                                const int* __restrict__ tgt,
                                                const int* __restrict__ base,
                                                const unsigned* __restrict__ elist,
                                                const float* __restrict__ Wo,
                                                float* __restrict__ logits_bp) {
    __shared__ float Acc[32 * 256];     // one 32-row chunk of Hh pre-activation (32 KB)
    __shared__ float val_s[NK];
    __shared__ int   node_s[NK];
    __shared__ int   tgt_s[NK];
    __shared__ unsigned em[4][128];     // bucketed: (row&31) | node<<5
    __shared__ float    ec[4][128];     // coef
    __shared__ int   bcnt[4];
    __shared__ float hvec[DHID];
    int bp = blockIdx.x;
    int hh = bp >> 8, b = (bp >> 5) & 7, blk = bp & 31;
    int ph = (b << 2) | hh;
    int tid = threadIdx.x;
    if (tid < 4) bcnt[tid] = 0;
    if (tid < NK) {
        int p = blk * NK + tid;
        node_s[tid] = order[ph * NN + p];
        val_s[tid]  = val[ph * NN + p];
        tgt_s[tid]  = tgt[ph * NN + p];
    }
    __syncthreads();
    int e0 = base[bp], ne = base[bp + 1] - e0;
    // bucket pass: decode each edge once
    for (int t = tid; t < ne; t += 256) {
        unsigned ent = elist[e0 + t];
        int ss = ent & 0xffff, sd = ent >> 16;
        int row = tgt_s[ss];
        int c = row >> 5;
        int slot = atomicAdd(&bcnt[c], 1);
        if (slot < 128) {
            em[c][slot] = (unsigned)((row & 31) | (node_s[sd] << 5));
            ec[c][slot] = val_s[ss] * val_s[sd] * val_s[sd];
        }
    }
    __syncthreads();
    int wave = tid >> 6, lane = tid & 63;
    float hsum = 0.f;
    for (int chunk = 0; chunk < 4; ++chunk) {
        for (int t4 = tid; t4 < 32 * 64; t4 += 256)
            ((float4*)Acc)[t4] = float4{0.f, 0.f, 0.f, 0.f};
        __syncthreads();
        int n = min(bcnt[chunk], 128);
        for (int i = wave; i < n; i += 4) {
            unsigned m = em[chunk][i];
            int row = m & 31, nd = m >> 5;
            float coef = ec[chunk][i];
            const float4 v = *(const float4*)(G + ((size_t)(b * NN + nd)) * DHID + lane * 4);
            float* mp = Acc + row * 256 + lane * 4;
            atomicAdd(mp + 0, coef * v.x);     // ds_add_f32: fire-and-forget, no RMW dep
            atomicAdd(mp + 1, coef * v.y);
            atomicAdd(mp + 2, coef * v.z);
            atomicAdd(mp + 3, coef * v.w);
        }
        __syncthreads();
#pragma unroll
        for (int r = 0; r < 32; ++r) hsum += fmaxf(Acc[r * 256 + tid], 0.f);
        __syncthreads();
    }
    hvec[tid] = hsum * (1.0f / NK);
    __syncthreads();
    if (tid < NCLS) {
        float s = 0.f;
        for (int q = 0; q < DHID; ++q) s = fmaf(hvec[q], Wo[q * NCLS + tid], s);
        logits_bp[bp * NCLS + tid] = s;
    }
}

// head-mean + log_softmax -> (8,32,16)
__global__ void k10_final(const float* __restrict__ logits_bp, float* __restrict__ out) {
    int t = threadIdx.x;                 // 256 = 8*32
    int b = t >> 5, blk = t & 31;
    float v[NCLS];
#pragma unroll
    for (int c = 0; c < NCLS; ++c) {
        float s = 0.f;
        for (int hh = 0; hh < NH; ++hh)
            s += logits_bp[(((hh * NB + b) * NJ) + blk) * NCLS + c];
        v[c] = s * 0.25f;
    }
    float mx = v[0];
#pragma unroll
    for (int c = 1; c < NCLS; ++c) mx = fmaxf(mx, v[c]);
    float se = 0.f;
#pragma unroll
    for (int c = 0; c < NCLS; ++c) se += expf(v[c] - mx);
    float lse = logf(se);
#pragma unroll
    for (int c = 0; c < NCLS; ++c) out[t * NCLS + c] = v[c] - mx - lse;
}

extern "C" void kernel_launch(void* const* d_in, const int* in_sizes, int n_in,
                              void* d_out, int out_size, void* d_ws, size_t ws_size,
                              hipStream_t stream) {
    const float* x  = (const float*)d_in[0];
    const float* wr = (const float*)d_in[1];
    const float* W1 = (const float*)d_in[2];
    const float* Wo = (const float*)d_in[3];
    const int*   ei = (const int*)d_in[4];

    char* ws = (char*)d_ws;
    int*      deg_i      = (int*)(ws + 0);          // 128 KB
    float*    rdeg       = (float*)(ws + 131072);   // 128 KB
    float*    scores_pre = (float*)(ws + 262144);   // 512 KB
    int*      iscore     = (int*)(ws + 786432);     // 512 KB
    float*    xapp       = (float*)(ws + 1310720);  // 16 MB
    float*    G          = (float*)(ws + 18087936); // 32 MB
    int*      order      = (int*)(ws + 51642368);   // 512 KB
    int*      pos        = (int*)(ws + 52166656);
    int*      tgt        = (int*)(ws + 52690944);
    float*    val        = (float*)(ws + 53215232);
    int*      cnt        = (int*)(ws + 53739520);   // 4 KB
    int*      fill       = (int*)(ws + 53743616);   // 4 KB
    int*      base       = (int*)(ws + 53747712);   // 8 KB
    int*      csr_src    = (int*)(ws + 53755904);   // 2 MB (lifetime ends at k4)
    unsigned short* w1t  = (unsigned short*)(ws + 55853056); // 128 KB (dead before elist writes)
    unsigned* elist      = (unsigned*)(ws + 53755904); // 8 MB (aliases csr_src+w1t; written at k8)
    float*    logits_bp  = (float*)(ws + 62144512); // 64 KB
    int*      nbase      = (int*)(ws + 62210048);   // 128 KB + 4
    int*      fill2      = (int*)(ws + 62341184);   // 128 KB
    unsigned* rec        = (unsigned*)xapp;                            // 8 MB  (xapp[0..8M), dead after kg_mfma)
    unsigned long long* sorted64 = (unsigned long long*)(ws + 9699328); // 1 MB (xapp[8M..9M), dead after kg_mfma)

    k0_init<<<512, 256, 0, stream>>>(deg_i, iscore, cnt, fill, fill2);
    k1_deg<<<2048, 256, 0, stream>>>(ei, deg_i);
    k1b_rdeg<<<128, 256, 0, stream>>>(deg_i, rdeg);
    kw_w1t<<<256, 256, 0, stream>>>(W1, w1t);
    k2_scores<<<512, 256, 0, stream>>>(x, wr, scores_pre);
    k3_scatter_scores<<<8192, 256, 0, stream>>>(ei, rdeg, scores_pre, iscore);
    k3b_scan<<<1, 1024, 0, stream>>>(deg_i, nbase);
    k3c_fill_csr<<<2048, 256, 0, stream>>>(ei, nbase, fill2, csr_src);
    k4_gather<<<8192, 256, 0, stream>>>(csr_src, nbase, rdeg, x, xapp);
    kg_mfma<<<512, 256, 0, stream>>>(x, xapp, w1t, G);        // last consumer of xapp
    k5a_chunk<<<256, 256, 0, stream>>>(scores_pre, iscore, deg_i, sorted64);
    k5b_rank<<<512, 256, 0, stream>>>(sorted64, order, pos, val);
    k5c_tgt<<<1024, 128, 0, stream>>>(order, tgt);
    k6_classify<<<8192, 256, 0, stream>>>(ei, pos, cnt, rec); // rec overwrites xapp (dead)
    k7_scan<<<1, 1024, 0, stream>>>(cnt, base);
    k8_fill<<<8192, 256, 0, stream>>>(rec, base, fill, elist); // elist overwrites csr/w1t (dead)
    k9_block<<<BPB, 256, 0, stream>>>(G, order, val, tgt, base, elist, Wo, logits_bp);
    k10_final<<<1, 256, 0, stream>>>(logits_bp, (float*)d_out);
}

// Round 6
// 368.658 us; speedup vs baseline: 1.2477x; 1.2477x over previous
//
#include <hip/hip_runtime.h>
#include <cmath>

#define NB 8
#define NN 4096
#define DF 128
#define NH 4
#define NJ 32
#define NK 128
#define NTOT (NB*NN)          // 32768
#define ETOT 524288           // 8 * 4096 * 16
#define BPB (NH*NB*NJ)        // 1024
#define DHID 256
#define NCLS 16
#define EMAX 640              // per-block kept-edge capacity (avg ~64)

#define FP_SCALE 4194304.0    // 2^22 fixed-point for deterministic score scatter
#define FP_INV   (1.0/4194304.0)

typedef short bf16x8 __attribute__((ext_vector_type(8)));
typedef float f32x4  __attribute__((ext_vector_type(4)));

__device__ __forceinline__ unsigned short f2bf(float f) {
    unsigned u = __float_as_uint(f);
    unsigned r = (u + 0x7FFFu + ((u >> 16) & 1u)) >> 16;   // RNE
    return (unsigned short)r;
}

// sortable u64 key: ascending k64 == (descending score, ascending idx) — matches argsort(-s) stable
__device__ __forceinline__ unsigned long long make_key(float sc, int p) {
    unsigned u = __float_as_uint(sc);
    unsigned s = u ^ ((unsigned)((int)u >> 31) | 0x80000000u);   // ascending-float map
    return ((unsigned long long)(s ^ 0xFFFFFFFFu) << 12) | (unsigned)p;
}

// ---------------- init ----------------
__global__ void k0_init(int* deg_i, int* iscore, int* cnt, int* fill, int* fill2) {
    int t = blockIdx.x * blockDim.x + threadIdx.x;
    if (t < NTOT * NH) iscore[t] = 0;
    if (t < NTOT) { deg_i[t] = 0; fill2[t] = 0; }
    if (t < BPB) { cnt[t] = 0; fill[t] = 0; }
}

// in-degree (int, exact, deterministic)
__global__ void k1_deg(const int* __restrict__ ei, int* deg_i) {
    int e = blockIdx.x * blockDim.x + threadIdx.x;
    if (e >= ETOT) return;
    atomicAdd(&deg_i[ei[ETOT + e]], 1);
}

// rdeg = 1/sqrt(1+indeg)
__global__ void k1b_rdeg(const int* __restrict__ deg_i, float* __restrict__ rdeg) {
    int t = blockIdx.x * blockDim.x + threadIdx.x;
    if (t >= NTOT) return;
    rdeg[t] = 1.0f / sqrtf((float)(1 + deg_i[t]));
}

// W1T_bf[n][k] = bf16(W1[k][n])   (256x256, coalesced reads)
__global__ void kw_w1t(const float* __restrict__ W1, unsigned short* __restrict__ w1t) {
    int t = blockIdx.x * 256 + threadIdx.x;     // 65536
    int k = t >> 8, n = t & 255;
    w1t[n * 256 + k] = f2bf(W1[k * DHID + n]);
}

// scores_pre = x_flat @ W_rank  (double accum: minimizes sort-flip risk)
__global__ void k2_scores(const float* __restrict__ x, const float* __restrict__ wr,
                          float* __restrict__ scores_pre) {
    int t = blockIdx.x * blockDim.x + threadIdx.x;
    if (t >= NTOT * NH) return;
    int g = t >> 2, hh = t & 3;
    const float* xr = x + (size_t)g * DF;
    double acc = 0.0;
    for (int d0 = 0; d0 < DF; ++d0) acc += (double)xr[d0] * (double)wr[d0 * NH + hh];
    scores_pre[t] = (float)acc;
}

// score scatter: fixed-point int atomics -> deterministic (f32 weight; quantization dominates)
__global__ void k3_scatter_scores(const int* __restrict__ ei, const float* __restrict__ rdeg,
                                  const float* __restrict__ scores_pre, int* iscore) {
    int t = blockIdx.x * blockDim.x + threadIdx.x;
    if (t >= ETOT * NH) return;
    int e = t >> 2, hh = t & 3;
    int s = ei[e], d = ei[ETOT + e];
    float w = rdeg[s] * rdeg[d];
    double term = (double)(w * scores_pre[s * NH + hh]);
    atomicAdd(&iscore[d * NH + hh], __double2int_rn(term * FP_SCALE));
}

// exclusive scan of in-degrees over 32768 nodes (single block)
__global__ __launch_bounds__(1024) void k3b_scan(const int* __restrict__ deg_i, int* nbase) {
    __shared__ int part[1024];
    int t = threadIdx.x;
    int base0 = t * 32;
    int local[32];
    int s = 0;
#pragma unroll
    for (int i = 0; i < 32; ++i) { local[i] = s; s += deg_i[base0 + i]; }
    part[t] = s;
    __syncthreads();
    for (int off = 1; off < 1024; off <<= 1) {
        int v = (t >= off) ? part[t - off] : 0;
        __syncthreads();
        part[t] += v;
        __syncthreads();
    }
    int myoff = (t == 0) ? 0 : part[t - 1];
#pragma unroll
    for (int i = 0; i < 32; ++i) nbase[base0 + i] = myoff + local[i];
    if (t == 1023) nbase[NTOT] = part[1023];
}

// fill dst-CSR: csr_src[nbase[d] + slot] = s
__global__ void k3c_fill_csr(const int* __restrict__ ei, const int* __restrict__ nbase,
                             int* fill2, int* __restrict__ csr_src) {
    int e = blockIdx.x * blockDim.x + threadIdx.x;
    if (e >= ETOT) return;
    int s = ei[e], d = ei[ETOT + e];
    int slot = atomicAdd(&fill2[d], 1);
    csr_src[nbase[d] + slot] = s;
}

// gather: xapp[g,:] = x[g,:]/deg + sum_{s in N(g)} rdeg[g]*rdeg[s]*x[s,:]
__global__ __launch_bounds__(256) void k4_gather(const int* __restrict__ csr_src,
                                                 const int* __restrict__ nbase,
                                                 const float* __restrict__ rdeg,
                                                 const float* __restrict__ x,
                                                 float* __restrict__ xapp) {
    int wv = (blockIdx.x * 256 + threadIdx.x) >> 6;   // node id
    if (wv >= NTOT) return;
    int lane = threadIdx.x & 63;
    float rd = rdeg[wv];
    float acc0 = x[(size_t)wv * DF + lane] * rd * rd;
    float acc1 = x[(size_t)wv * DF + 64 + lane] * rd * rd;
    int t0 = nbase[wv], t1 = nbase[wv + 1];
    for (int t = t0; t < t1; ++t) {
        int s = csr_src[t];
        float w = rd * rdeg[s];
        acc0 += w * x[(size_t)s * DF + lane];
        acc1 += w * x[(size_t)s * DF + 64 + lane];
    }
    xapp[(size_t)wv * DF + lane] = acc0;
    xapp[(size_t)wv * DF + 64 + lane] = acc1;
}

// G = concat(x, xapp) @ W1 via bf16 MFMA.  M=32768, N=256, K=256.
__global__ __launch_bounds__(256) void kg_mfma(const float* __restrict__ x,
                                               const float* __restrict__ xapp,
                                               const unsigned short* __restrict__ w1t,
                                               float* __restrict__ G) {
    __shared__ __align__(16) unsigned short As[128 * 64];  // [row][k] swizzled
    __shared__ __align__(16) unsigned short Bs[128 * 64];  // [n][k]   swizzled
    int bid = blockIdx.x;
    int m0 = (bid >> 1) * 128, n0 = (bid & 1) * 128;
    int tid = threadIdx.x, lane = tid & 63, wid = tid >> 6;
    int wr = wid >> 1, wc = wid & 1;
    f32x4 acc[4][4];
#pragma unroll
    for (int mi = 0; mi < 4; ++mi)
#pragma unroll
        for (int ni = 0; ni < 4; ++ni) acc[mi][ni] = f32x4{0.f, 0.f, 0.f, 0.f};

    for (int kk = 0; kk < 4; ++kk) {
        int k0 = kk * 64;
        const float* Asrc = (k0 < 128) ? x : xapp;
        int kbase = k0 & 127;
#pragma unroll
        for (int i = 0; i < 4; ++i) {
            int gi = tid + i * 256;
            int r = gi >> 3, c = gi & 7;
            int csrc = c ^ (r & 7);
            const float* sp = Asrc + (size_t)(m0 + r) * DF + kbase + csrc * 8;
            float4 lo = *(const float4*)sp;
            float4 hi = *(const float4*)(sp + 4);
            unsigned short u[8] = {f2bf(lo.x), f2bf(lo.y), f2bf(lo.z), f2bf(lo.w),
                                   f2bf(hi.x), f2bf(hi.y), f2bf(hi.z), f2bf(hi.w)};
            *(bf16x8*)&As[r * 64 + c * 8] = *(bf16x8*)u;
        }
#pragma unroll
        for (int i = 0; i < 4; ++i) {
            int gi = tid + i * 256;
            int r = gi >> 3, c = gi & 7;
            int csrc = c ^ (r & 7);
            *(bf16x8*)&Bs[r * 64 + c * 8] =
                *(const bf16x8*)(w1t + (size_t)(n0 + r) * 256 + k0 + csrc * 8);
        }
        __syncthreads();
#pragma unroll
        for (int ks = 0; ks < 2; ++ks) {
            bf16x8 af[4], bfr[4];
#pragma unroll
            for (int mi = 0; mi < 4; ++mi) {
                int r = wr * 64 + mi * 16 + (lane & 15);
                int gl = ks * 4 + (lane >> 4);
                af[mi] = *(const bf16x8*)&As[r * 64 + (gl ^ (r & 7)) * 8];
            }
#pragma unroll
            for (int ni = 0; ni < 4; ++ni) {
                int r = wc * 64 + ni * 16 + (lane & 15);
                int gl = ks * 4 + (lane >> 4);
                bfr[ni] = *(const bf16x8*)&Bs[r * 64 + (gl ^ (r & 7)) * 8];
            }
#pragma unroll
            for (int mi = 0; mi < 4; ++mi)
#pragma unroll
                for (int ni = 0; ni < 4; ++ni)
                    acc[mi][ni] = __builtin_amdgcn_mfma_f32_16x16x32_bf16(
                        af[mi], bfr[ni], acc[mi][ni], 0, 0, 0);
        }
        __syncthreads();
    }
#pragma unroll
    for (int mi = 0; mi < 4; ++mi) {
        int rbase = m0 + wr * 64 + mi * 16 + (lane >> 4) * 4;
#pragma unroll
        for (int ni = 0; ni < 4; ++ni) {
            int col = n0 + wc * 64 + ni * 16 + (lane & 15);
#pragma unroll
            for (int j = 0; j < 4; ++j)
                G[(size_t)(rbase + j) * DHID + col] = acc[mi][ni][j];
        }
    }
}

// sort phase A: 512-element chunk bitonic sort on packed u64 keys (one block per chunk)
__global__ __launch_bounds__(256) void k5a_chunk(const float* __restrict__ scores_pre,
                                                 const int* __restrict__ iscore,
                                                 const int* __restrict__ deg_i,
                                                 unsigned long long* __restrict__ sorted64) {
    __shared__ unsigned long long sk[512];
    int blk = blockIdx.x;            // seg*8 + chunk
    int seg = blk >> 3, chunk = blk & 7;
    int b = seg >> 2, hh = seg & 3;
    int tid = threadIdx.x;
    for (int i = tid; i < 512; i += 256) {
        int p = chunk * 512 + i;
        int g = b * NN + p;
        float dg = (float)(1 + deg_i[g]);
        float sc = scores_pre[g * NH + hh] / dg + (float)((double)iscore[g * NH + hh] * FP_INV);
        sk[i] = make_key(sc, p);
    }
    __syncthreads();
    for (int size = 2; size <= 512; size <<= 1) {
        for (int stride = size >> 1; stride > 0; stride >>= 1) {
            for (int p = tid; p < 512; p += 256) {
                int q = p ^ stride;
                if (q > p) {
                    unsigned long long kp = sk[p], kq = sk[q];
                    bool before_qp = (kq < kp);
                    bool asc = ((p & size) == 0);
                    if (asc ? before_qp : !before_qp) { sk[p] = kq; sk[q] = kp; }
                }
            }
            __syncthreads();
        }
    }
    for (int i = tid; i < 512; i += 256)
        sorted64[seg * NN + chunk * 512 + i] = sk[i];
}

// sort phase B: rank via binary searches over the other 7 sorted chunks (no barriers)
__global__ __launch_bounds__(256) void k5b_rank(const unsigned long long* __restrict__ sorted64,
                                                int* __restrict__ order, int* __restrict__ pos,
                                                float* __restrict__ val) {
    int t = blockIdx.x * 256 + threadIdx.x;      // 131072
    int seg = t >> 12, i = t & 4095;
    int chunk = i >> 9, slot = i & 511;
    const unsigned long long* segp = sorted64 + (size_t)seg * NN;
    unsigned long long k = segp[chunk * 512 + slot];
    int rank = slot;
#pragma unroll
    for (int c = 0; c < 8; ++c) {
        if (c == chunk) continue;
        const unsigned long long* cp = segp + c * 512;
        int lo = 0, hi = 512;
        while (lo < hi) { int mid = (lo + hi) >> 1; lo = (cp[mid] < k) ? mid + 1 : lo; hi = (cp[mid] < k) ? hi : mid; }
        rank += lo;
    }
    int p = (int)(k & 4095u);
    pos[seg * NN + p] = rank;
    order[seg * NN + rank] = p;
    unsigned s = (unsigned)(k >> 12) ^ 0xFFFFFFFFu;
    unsigned u = s ^ (((int)s >= 0) ? 0xFFFFFFFFu : 0x80000000u);
    float sc = __uint_as_float(u);
    val[seg * NN + rank] = 1.0f / (1.0f + expf(-sc));
}

// sort phase C: tgt = rank of order[p] by node-id within its 128-block
__global__ __launch_bounds__(128) void k5c_tgt(const int* __restrict__ order,
                                               int* __restrict__ tgt) {
    __shared__ int o[128];
    int base = blockIdx.x * 128;     // = seg*4096 + j*128
    int tid = threadIdx.x;
    o[tid] = order[base + tid];
    __syncthreads();
    int me = o[tid];
    int r = 0;
#pragma unroll 16
    for (int s2 = 0; s2 < 128; ++s2) r += (o[s2] < me) ? 1 : 0;
    tgt[base + tid] = r;
}

// classify each (edge, head): compute block-pair id + slots, count per block, emit record
__global__ void k6_classify(const int* __restrict__ ei, const int* __restrict__ pos,
                            int* cnt, unsigned* __restrict__ rec) {
    int t = blockIdx.x * blockDim.x + threadIdx.x;
    if (t >= ETOT * NH) return;
    int e = t >> 2, hh = t & 3;
    int s = ei[e], d = ei[ETOT + e];
    int b = s >> 12, sl = s & 4095, dl = d & 4095;
    int ph = (b << 2) | hh;
    int ps = pos[ph * NN + sl], pd = pos[ph * NN + dl];
    unsigned r = 0xFFFFFFFFu;
    if ((ps >> 7) == (pd >> 7)) {
        int bpid = ((hh * NB + b) * NJ) + (ps >> 7);
        atomicAdd(&cnt[bpid], 1);
        r = ((unsigned)bpid << 14) | ((unsigned)(ps & 127) << 7) | (unsigned)(pd & 127);
    }
    rec[t] = r;
}

__global__ __launch_bounds__(1024) void k7_scan(const int* __restrict__ cnt, int* base) {
    __shared__ int sh[BPB];
    int t = threadIdx.x;
    sh[t] = cnt[t];
    __syncthreads();
    for (int off = 1; off < BPB; off <<= 1) {
        int v = (t >= off) ? sh[t - off] : 0;
        __syncthreads();
        sh[t] += v;
        __syncthreads();
    }
    base[t + 1] = sh[t];
    if (t == 0) base[0] = 0;
}

__global__ void k8_fill(const unsigned* __restrict__ rec, const int* __restrict__ base,
                        int* fill, unsigned* elist) {
    int t = blockIdx.x * blockDim.x + threadIdx.x;
    if (t >= ETOT * NH) return;
    unsigned r = rec[t];
    if (r == 0xFFFFFFFFu) return;
    int bpid = r >> 14;
    int ss = (r >> 7) & 127, sd = r & 127;
    int k2 = atomicAdd(&fill[bpid], 1);
    elist[base[bpid] + k2] = (unsigned)(ss | (sd << 16));
}

// per-block: group kept edges by output row, then column-parallel register accumulation.
// Hh[row,:] = relu(sum_{edges->row} coef * G[node,:]); hsum[col] = sum_rows; @ W_out.
__global__ __launch_bounds__(256) void k9_block(const float* __restrict__ G,
                                                const int* __restrict__ order,
                                                const float* __restrict__ val,
                                                const int* __restrict__ tgt,
                                                const int* __restrict__ base,
                                                const unsigned* __restrict__ elist,
                                                const float* __restrict__ Wo,
                                                float* __restrict__ logits_bp) {
    __shared__ float val_s[NK];
    __shared__ int   node_s[NK];
    __shared__ int   tgt_s[NK];
    __shared__ int   rcnt[NK];        // edges per output row
    __shared__ int   rend[NK];        // inclusive scan
    __shared__ int   rfill[NK];
    __shared__ int   es_node[EMAX];   // row-grouped edge: source node id
    __shared__ float es_coef[EMAX];   // row-grouped edge: coefficient
    __shared__ float hvec[DHID];
    int bp = blockIdx.x;
    int hh = bp >> 8, b = (bp >> 5) & 7, blk = bp & 31;
    int ph = (b << 2) | hh;
    int tid = threadIdx.x;
    if (tid < NK) {
        int p = blk * NK + tid;
        node_s[tid] = order[ph * NN + p];
        val_s[tid]  = val[ph * NN + p];
        tgt_s[tid]  = tgt[ph * NN + p];
        rcnt[tid] = 0; rfill[tid] = 0;
    }
    __syncthreads();
    int e0 = base[bp], ne = min(base[bp + 1] - e0, EMAX);
    // count edges per row
    for (int t = tid; t < ne; t += 256)
        atomicAdd(&rcnt[tgt_s[elist[e0 + t] & 0xffff]], 1);
    __syncthreads();
    // inclusive scan over 128 rows
    if (tid < NK) rend[tid] = rcnt[tid];
    __syncthreads();
    for (int off = 1; off < NK; off <<= 1) {
        int v = 0;
        if (tid < NK && tid >= off) v = rend[tid - off];
        __syncthreads();
        if (tid < NK) rend[tid] += v;
        __syncthreads();
    }
    // scatter edges grouped by row
    for (int t = tid; t < ne; t += 256) {
        unsigned ent = elist[e0 + t];
        int ss = ent & 0xffff, sd = ent >> 16;
        int row = tgt_s[ss];
        int slot = atomicAdd(&rfill[row], 1);
        int p0 = rend[row] - rcnt[row] + slot;
        es_node[p0] = node_s[sd];
        es_coef[p0] = val_s[ss] * val_s[sd] * val_s[sd];
    }
    __syncthreads();
    // column-parallel: thread owns column tid; loop rows, register accumulate
    float hsum = 0.f;
    for (int r = 0; r < NK; ++r) {
        int n = rcnt[r];
        if (n == 0) continue;                 // ~60% of rows empty: relu(0)=0
        int s0 = rend[r] - n;
        float m = 0.f;
        for (int i = 0; i < n; ++i)
            m = fmaf(es_coef[s0 + i],
                     G[((size_t)(b * NN + es_node[s0 + i])) * DHID + tid], m);
        hsum += fmaxf(m, 0.f);
    }
    hvec[tid] = hsum * (1.0f / NK);
    __syncthreads();
    if (tid < NCLS) {
        float s = 0.f;
        for (int q = 0; q < DHID; ++q) s = fmaf(hvec[q], Wo[q * NCLS + tid], s);
        logits_bp[bp * NCLS + tid] = s;
    }
}

// head-mean + log_softmax -> (8,32,16)
__global__ void k10_final(const float* __restrict__ logits_bp, float* __restrict__ out) {
    int t = threadIdx.x;                 // 256 = 8*32
    int b = t >> 5, blk = t & 31;
    float v[NCLS];
#pragma unroll
    for (int c = 0; c < NCLS; ++c) {
        float s = 0.f;
        for (int hh = 0; hh < NH; ++hh)
            s += logits_bp[(((hh * NB + b) * NJ) + blk) * NCLS + c];
        v[c] = s * 0.25f;
    }
    float mx = v[0];
#pragma unroll
    for (int c = 1; c < NCLS; ++c) mx = fmaxf(mx, v[c]);
    float se = 0.f;
#pragma unroll
    for (int c = 0; c < NCLS; ++c) se += expf(v[c] - mx);
    float lse = logf(se);
#pragma unroll
    for (int c = 0; c < NCLS; ++c) out[t * NCLS + c] = v[c] - mx - lse;
}

extern "C" void kernel_launch(void* const* d_in, const int* in_sizes, int n_in,
                              void* d_out, int out_size, void* d_ws, size_t ws_size,
                              hipStream_t stream) {
    const float* x  = (const float*)d_in[0];
    const float* wr = (const float*)d_in[1];
    const float* W1 = (const float*)d_in[2];
    const float* Wo = (const float*)d_in[3];
    const int*   ei = (const int*)d_in[4];

    char* ws = (char*)d_ws;
    int*      deg_i      = (int*)(ws + 0);          // 128 KB
    float*    rdeg       = (float*)(ws + 131072);   // 128 KB
    float*    scores_pre = (float*)(ws + 262144);   // 512 KB
    int*      iscore     = (int*)(ws + 786432);     // 512 KB
    float*    xapp       = (float*)(ws + 1310720);  // 16 MB
    float*    G          = (float*)(ws + 18087936); // 32 MB
    int*      order      = (int*)(ws + 51642368);   // 512 KB
    int*      pos        = (int*)(ws + 52166656);
    int*      tgt        = (int*)(ws + 52690944);
    float*    val        = (float*)(ws + 53215232);
    int*      cnt        = (int*)(ws + 53739520);   // 4 KB
    int*      fill       = (int*)(ws + 53743616);   // 4 KB
    int*      base       = (int*)(ws + 53747712);   // 8 KB
    int*      csr_src    = (int*)(ws + 53755904);   // 2 MB (lifetime ends at k4)
    unsigned short* w1t  = (unsigned short*)(ws + 55853056); // 128 KB (dead before elist writes)
    unsigned* elist      = (unsigned*)(ws + 53755904); // 8 MB (aliases csr_src+w1t; written at k8)
    float*    logits_bp  = (float*)(ws + 62144512); // 64 KB
    int*      nbase      = (int*)(ws + 62210048);   // 128 KB + 4
    int*      fill2      = (int*)(ws + 62341184);   // 128 KB
    unsigned* rec        = (unsigned*)xapp;                            // 8 MB  (xapp[0..8M), dead after kg_mfma)
    unsigned long long* sorted64 = (unsigned long long*)(ws + 9699328); // 1 MB (xapp[8M..9M), dead after kg_mfma)

    k0_init<<<512, 256, 0, stream>>>(deg_i, iscore, cnt, fill, fill2);
    k1_deg<<<2048, 256, 0, stream>>>(ei, deg_i);
    k1b_rdeg<<<128, 256, 0, stream>>>(deg_i, rdeg);
    kw_w1t<<<256, 256, 0, stream>>>(W1, w1t);
    k2_scores<<<512, 256, 0, stream>>>(x, wr, scores_pre);
    k3_scatter_scores<<<8192, 256, 0, stream>>>(ei, rdeg, scores_pre, iscore);
    k3b_scan<<<1, 1024, 0, stream>>>(deg_i, nbase);
    k3c_fill_csr<<<2048, 256, 0, stream>>>(ei, nbase, fill2, csr_src);
    k4_gather<<<8192, 256, 0, stream>>>(csr_src, nbase, rdeg, x, xapp);
    kg_mfma<<<512, 256, 0, stream>>>(x, xapp, w1t, G);        // last consumer of xapp
    k5a_chunk<<<256, 256, 0, stream>>>(scores_pre, iscore, deg_i, sorted64);
    k5b_rank<<<512, 256, 0, stream>>>(sorted64, order, pos, val);
    k5c_tgt<<<1024, 128, 0, stream>>>(order, tgt);
    k6_classify<<<8192, 256, 0, stream>>>(ei, pos, cnt, rec); // rec overwrites xapp (dead)
    k7_scan<<<1, 1024, 0, stream>>>(cnt, base);
    k8_fill<<<8192, 256, 0, stream>>>(rec, base, fill, elist); // elist overwrites csr/w1t (dead)
    k9_block<<<BPB, 256, 0, stream>>>(G, order, val, tgt, base, elist, Wo, logits_bp);
    k10_final<<<1, 256, 0, stream>>>(logits_bp, (float*)d_out);
}

// Round 7
// 274.346 us; speedup vs baseline: 1.6766x; 1.3438x over previous
//
#include <hip/hip_runtime.h>
#include <cmath>

#define NB 8
#define NN 4096
#define DF 128
#define NH 4
#define NJ 32
#define NK 128
#define NTOT (NB*NN)          // 32768
#define ETOT 524288           // 8 * 4096 * 16
#define BPB (NH*NB*NJ)        // 1024
#define DHID 256
#define NCLS 16
#define CAP_PB 96             // per (part, blk) LDS bucket capacity (avg ~8)
#define CAP_BP 512            // per-bpid elist segment capacity (avg ~64)

#define FP_SCALE 4194304.0    // 2^22 fixed-point for deterministic score scatter
#define FP_INV   (1.0/4194304.0)

typedef short bf16x8 __attribute__((ext_vector_type(8)));
typedef float f32x4  __attribute__((ext_vector_type(4)));

__device__ __forceinline__ unsigned short f2bf(float f) {
    unsigned u = __float_as_uint(f);
    unsigned r = (u + 0x7FFFu + ((u >> 16) & 1u)) >> 16;   // RNE
    return (unsigned short)r;
}

// sortable u64 key: ascending k64 == (descending score, ascending idx) — matches argsort(-s) stable
__device__ __forceinline__ unsigned long long make_key(float sc, int p) {
    unsigned u = __float_as_uint(sc);
    unsigned s = u ^ ((unsigned)((int)u >> 31) | 0x80000000u);   // ascending-float map
    return ((unsigned long long)(s ^ 0xFFFFFFFFu) << 12) | (unsigned)p;
}

// ---------------- init ----------------
__global__ void k0_init(int* deg_i, int* iscore, int* fill, int* fill2) {
    int t = blockIdx.x * blockDim.x + threadIdx.x;
    if (t < NTOT * NH) iscore[t] = 0;
    if (t < NTOT) { deg_i[t] = 0; fill2[t] = 0; }
    if (t < BPB) fill[t] = 0;
}

// in-degree (int, exact, deterministic)
__global__ void k1_deg(const int* __restrict__ ei, int* deg_i) {
    int e = blockIdx.x * blockDim.x + threadIdx.x;
    if (e >= ETOT) return;
    atomicAdd(&deg_i[ei[ETOT + e]], 1);
}

// rdeg = 1/sqrt(1+indeg)
__global__ void k1b_rdeg(const int* __restrict__ deg_i, float* __restrict__ rdeg) {
    int t = blockIdx.x * blockDim.x + threadIdx.x;
    if (t >= NTOT) return;
    rdeg[t] = 1.0f / sqrtf((float)(1 + deg_i[t]));
}

// W1T_bf[n][k] = bf16(W1[k][n])   (256x256, coalesced reads)
__global__ void kw_w1t(const float* __restrict__ W1, unsigned short* __restrict__ w1t) {
    int t = blockIdx.x * 256 + threadIdx.x;     // 65536
    int k = t >> 8, n = t & 255;
    w1t[n * 256 + k] = f2bf(W1[k * DHID + n]);
}

// scores_pre = x_flat @ W_rank  (double accum: minimizes sort-flip risk)
__global__ void k2_scores(const float* __restrict__ x, const float* __restrict__ wr,
                          float* __restrict__ scores_pre) {
    int t = blockIdx.x * blockDim.x + threadIdx.x;
    if (t >= NTOT * NH) return;
    int g = t >> 2, hh = t & 3;
    const float* xr = x + (size_t)g * DF;
    double acc = 0.0;
    for (int d0 = 0; d0 < DF; ++d0) acc += (double)xr[d0] * (double)wr[d0 * NH + hh];
    scores_pre[t] = (float)acc;
}

// score scatter: fixed-point int atomics -> deterministic (f32 weight; quantization dominates)
__global__ void k3_scatter_scores(const int* __restrict__ ei, const float* __restrict__ rdeg,
                                  const float* __restrict__ scores_pre, int* iscore) {
    int t = blockIdx.x * blockDim.x + threadIdx.x;
    if (t >= ETOT * NH) return;
    int e = t >> 2, hh = t & 3;
    int s = ei[e], d = ei[ETOT + e];
    float w = rdeg[s] * rdeg[d];
    double term = (double)(w * scores_pre[s * NH + hh]);
    atomicAdd(&iscore[d * NH + hh], __double2int_rn(term * FP_SCALE));
}

// exclusive scan of in-degrees over 32768 nodes (single block)
__global__ __launch_bounds__(1024) void k3b_scan(const int* __restrict__ deg_i, int* nbase) {
    __shared__ int part[1024];
    int t = threadIdx.x;
    int base0 = t * 32;
    int local[32];
    int s = 0;
#pragma unroll
    for (int i = 0; i < 32; ++i) { local[i] = s; s += deg_i[base0 + i]; }
    part[t] = s;
    __syncthreads();
    for (int off = 1; off < 1024; off <<= 1) {
        int v = (t >= off) ? part[t - off] : 0;
        __syncthreads();
        part[t] += v;
        __syncthreads();
    }
    int myoff = (t == 0) ? 0 : part[t - 1];
#pragma unroll
    for (int i = 0; i < 32; ++i) nbase[base0 + i] = myoff + local[i];
    if (t == 1023) nbase[NTOT] = part[1023];
}

// fill dst-CSR: csr_src[nbase[d] + slot] = s
__global__ void k3c_fill_csr(const int* __restrict__ ei, const int* __restrict__ nbase,
                             int* fill2, int* __restrict__ csr_src) {
    int e = blockIdx.x * blockDim.x + threadIdx.x;
    if (e >= ETOT) return;
    int s = ei[e], d = ei[ETOT + e];
    int slot = atomicAdd(&fill2[d], 1);
    csr_src[nbase[d] + slot] = s;
}

// gather: xapp[g,:] = x[g,:]/deg + sum_{s in N(g)} rdeg[g]*rdeg[s]*x[s,:]
__global__ __launch_bounds__(256) void k4_gather(const int* __restrict__ csr_src,
                                                 const int* __restrict__ nbase,
                                                 const float* __restrict__ rdeg,
                                                 const float* __restrict__ x,
                                                 float* __restrict__ xapp) {
    int wv = (blockIdx.x * 256 + threadIdx.x) >> 6;   // node id
    if (wv >= NTOT) return;
    int lane = threadIdx.x & 63;
    float rd = rdeg[wv];
    float acc0 = x[(size_t)wv * DF + lane] * rd * rd;
    float acc1 = x[(size_t)wv * DF + 64 + lane] * rd * rd;
    int t0 = nbase[wv], t1 = nbase[wv + 1];
    for (int t = t0; t < t1; ++t) {
        int s = csr_src[t];
        float w = rd * rdeg[s];
        acc0 += w * x[(size_t)s * DF + lane];
        acc1 += w * x[(size_t)s * DF + 64 + lane];
    }
    xapp[(size_t)wv * DF + lane] = acc0;
    xapp[(size_t)wv * DF + 64 + lane] = acc1;
}

// G = concat(x, xapp) @ W1 via bf16 MFMA.  M=32768, N=256, K=256.
__global__ __launch_bounds__(256) void kg_mfma(const float* __restrict__ x,
                                               const float* __restrict__ xapp,
                                               const unsigned short* __restrict__ w1t,
                                               float* __restrict__ G) {
    __shared__ __align__(16) unsigned short As[128 * 64];  // [row][k] swizzled
    __shared__ __align__(16) unsigned short Bs[128 * 64];  // [n][k]   swizzled
    int bid = blockIdx.x;
    int m0 = (bid >> 1) * 128, n0 = (bid & 1) * 128;
    int tid = threadIdx.x, lane = tid & 63, wid = tid >> 6;
    int wr = wid >> 1, wc = wid & 1;
    f32x4 acc[4][4];
#pragma unroll
    for (int mi = 0; mi < 4; ++mi)
#pragma unroll
        for (int ni = 0; ni < 4; ++ni) acc[mi][ni] = f32x4{0.f, 0.f, 0.f, 0.f};

    for (int kk = 0; kk < 4; ++kk) {
        int k0 = kk * 64;
        const float* Asrc = (k0 < 128) ? x : xapp;
        int kbase = k0 & 127;
#pragma unroll
        for (int i = 0; i < 4; ++i) {
            int gi = tid + i * 256;
            int r = gi >> 3, c = gi & 7;
            int csrc = c ^ (r & 7);
            const float* sp = Asrc + (size_t)(m0 + r) * DF + kbase + csrc * 8;
            float4 lo = *(const float4*)sp;
            float4 hi = *(const float4*)(sp + 4);
            unsigned short u[8] = {f2bf(lo.x), f2bf(lo.y), f2bf(lo.z), f2bf(lo.w),
                                   f2bf(hi.x), f2bf(hi.y), f2bf(hi.z), f2bf(hi.w)};
            *(bf16x8*)&As[r * 64 + c * 8] = *(bf16x8*)u;
        }
#pragma unroll
        for (int i = 0; i < 4; ++i) {
            int gi = tid + i * 256;
            int r = gi >> 3, c = gi & 7;
            int csrc = c ^ (r & 7);
            *(bf16x8*)&Bs[r * 64 + c * 8] =
                *(const bf16x8*)(w1t + (size_t)(n0 + r) * 256 + k0 + csrc * 8);
        }
        __syncthreads();
#pragma unroll
        for (int ks = 0; ks < 2; ++ks) {
            bf16x8 af[4], bfr[4];
#pragma unroll
            for (int mi = 0; mi < 4; ++mi) {
                int r = wr * 64 + mi * 16 + (lane & 15);
                int gl = ks * 4 + (lane >> 4);
                af[mi] = *(const bf16x8*)&As[r * 64 + (gl ^ (r & 7)) * 8];
            }
#pragma unroll
            for (int ni = 0; ni < 4; ++ni) {
                int r = wc * 64 + ni * 16 + (lane & 15);
                int gl = ks * 4 + (lane >> 4);
                bfr[ni] = *(const bf16x8*)&Bs[r * 64 + (gl ^ (r & 7)) * 8];
            }
#pragma unroll
            for (int mi = 0; mi < 4; ++mi)
#pragma unroll
                for (int ni = 0; ni < 4; ++ni)
                    acc[mi][ni] = __builtin_amdgcn_mfma_f32_16x16x32_bf16(
                        af[mi], bfr[ni], acc[mi][ni], 0, 0, 0);
        }
        __syncthreads();
    }
#pragma unroll
    for (int mi = 0; mi < 4; ++mi) {
        int rbase = m0 + wr * 64 + mi * 16 + (lane >> 4) * 4;
#pragma unroll
        for (int ni = 0; ni < 4; ++ni) {
            int col = n0 + wc * 64 + ni * 16 + (lane & 15);
#pragma unroll
            for (int j = 0; j < 4; ++j)
                G[(size_t)(rbase + j) * DHID + col] = acc[mi][ni][j];
        }
    }
}

// sort phase A: 512-element chunk bitonic sort on packed u64 keys (one block per chunk)
__global__ __launch_bounds__(256) void k5a_chunk(const float* __restrict__ scores_pre,
                                                 const int* __restrict__ iscore,
                                                 const int* __restrict__ deg_i,
                                                 unsigned long long* __restrict__ sorted64) {
    __shared__ unsigned long long sk[512];
    int blk = blockIdx.x;            // seg*8 + chunk
    int seg = blk >> 3, chunk = blk & 7;
    int b = seg >> 2, hh = seg & 3;
    int tid = threadIdx.x;
    for (int i = tid; i < 512; i += 256) {
        int p = chunk * 512 + i;
        int g = b * NN + p;
        float dg = (float)(1 + deg_i[g]);
        float sc = scores_pre[g * NH + hh] / dg + (float)((double)iscore[g * NH + hh] * FP_INV);
        sk[i] = make_key(sc, p);
    }
    __syncthreads();
    for (int size = 2; size <= 512; size <<= 1) {
        for (int stride = size >> 1; stride > 0; stride >>= 1) {
            for (int p = tid; p < 512; p += 256) {
                int q = p ^ stride;
                if (q > p) {
                    unsigned long long kp = sk[p], kq = sk[q];
                    bool before_qp = (kq < kp);
                    bool asc = ((p & size) == 0);
                    if (asc ? before_qp : !before_qp) { sk[p] = kq; sk[q] = kp; }
                }
            }
            __syncthreads();
        }
    }
    for (int i = tid; i < 512; i += 256)
        sorted64[seg * NN + chunk * 512 + i] = sk[i];
}

// sort phase B: rank via binary searches over the other 7 sorted chunks (no barriers)
__global__ __launch_bounds__(256) void k5b_rank(const unsigned long long* __restrict__ sorted64,
                                                int* __restrict__ order, int* __restrict__ pos,
                                                float* __restrict__ val) {
    int t = blockIdx.x * 256 + threadIdx.x;      // 131072
    int seg = t >> 12, i = t & 4095;
    int chunk = i >> 9, slot = i & 511;
    const unsigned long long* segp = sorted64 + (size_t)seg * NN;
    unsigned long long k = segp[chunk * 512 + slot];
    int rank = slot;
#pragma unroll
    for (int c = 0; c < 8; ++c) {
        if (c == chunk) continue;
        const unsigned long long* cp = segp + c * 512;
        int lo = 0, hi = 512;
        while (lo < hi) { int mid = (lo + hi) >> 1; lo = (cp[mid] < k) ? mid + 1 : lo; hi = (cp[mid] < k) ? hi : mid; }
        rank += lo;
    }
    int p = (int)(k & 4095u);
    pos[seg * NN + p] = rank;
    order[seg * NN + rank] = p;
    unsigned s = (unsigned)(k >> 12) ^ 0xFFFFFFFFu;
    unsigned u = s ^ (((int)s >= 0) ? 0xFFFFFFFFu : 0x80000000u);
    float sc = __uint_as_float(u);
    val[seg * NN + rank] = 1.0f / (1.0f + expf(-sc));
}

// sort phase C: tgt = rank of order[p] by node-id within its 128-block
__global__ __launch_bounds__(128) void k5c_tgt(const int* __restrict__ order,
                                               int* __restrict__ tgt) {
    __shared__ int o[128];
    int base = blockIdx.x * 128;     // = seg*4096 + j*128
    int tid = threadIdx.x;
    o[tid] = order[base + tid];
    __syncthreads();
    int me = o[tid];
    int r = 0;
#pragma unroll 16
    for (int s2 = 0; s2 < 128; ++s2) r += (o[s2] < me) ? 1 : 0;
    tgt[base + tid] = r;
}

// bin kept edges by block-pair id: LDS-staged pos row, LDS buckets, block-aggregated
// global atomics (one per nonzero bucket). Replaces classify+scan+fill pipeline.
__global__ __launch_bounds__(256) void k6_bin(const int* __restrict__ ei,
                                              const int* __restrict__ pos,
                                              int* fill, unsigned* __restrict__ elist) {
    __shared__ unsigned short pos_l[NN];      // 8 KB (pos values < 4096)
    __shared__ unsigned buf[NJ][CAP_PB];      // 12 KB
    __shared__ int lcnt[NJ];
    __shared__ int gbase[NJ];
    int blkid = blockIdx.x;        // ph*8 + part
    int ph = blkid >> 3, part = blkid & 7;
    int b = ph >> 2, hh = ph & 3;
    int tid = threadIdx.x;
    for (int i = tid; i < NN; i += 256) pos_l[i] = (unsigned short)pos[ph * NN + i];
    if (tid < NJ) lcnt[tid] = 0;
    __syncthreads();
    int ebase = b * 65536 + part * 8192;
    for (int i = tid; i < 8192; i += 256) {
        int e = ebase + i;
        int s = ei[e], d = ei[ETOT + e];
        int ps = pos_l[s & 4095], pd = pos_l[d & 4095];
        if ((ps >> 7) == (pd >> 7)) {
            int blk = ps >> 7;
            int slot = atomicAdd(&lcnt[blk], 1);
            if (slot < CAP_PB)
                buf[blk][slot] = (unsigned)((ps & 127) | ((pd & 127) << 16));
        }
    }
    __syncthreads();
    if (tid < NJ) {
        int n = min(lcnt[tid], CAP_PB);
        lcnt[tid] = n;
        gbase[tid] = atomicAdd(&fill[((hh * NB + b) * NJ) + tid], n);
    }
    __syncthreads();
    for (int t = tid; t < NJ * CAP_PB; t += 256) {
        int blk = t / CAP_PB, i = t % CAP_PB;
        if (i < lcnt[blk]) {
            int g0 = gbase[blk] + i;
            if (g0 < CAP_BP) {
                int bpid = ((hh * NB + b) * NJ) + blk;
                elist[bpid * CAP_BP + g0] = buf[blk][i];
            }
        }
    }
}

// per-block: group kept edges by output row, then column-parallel register accumulation.
// Hh[row,:] = relu(sum_{edges->row} coef * G[node,:]); hsum[col] = sum_rows; @ W_out.
__global__ __launch_bounds__(256) void k9_block(const float* __restrict__ G,
                                                const int* __restrict__ order,
                                                const float* __restrict__ val,
                                                const int* __restrict__ tgt,
                                                const int* __restrict__ fill,
                                                const unsigned* __restrict__ elist,
                                                const float* __restrict__ Wo,
                                                float* __restrict__ logits_bp) {
    __shared__ float val_s[NK];
    __shared__ int   node_s[NK];
    __shared__ int   tgt_s[NK];
    __shared__ int   rcnt[NK];        // edges per output row
    __shared__ int   rend[NK];        // inclusive scan
    __shared__ int   rfill[NK];
    __shared__ int   es_node[CAP_BP]; // row-grouped edge: source node id
    __shared__ float es_coef[CAP_BP]; // row-grouped edge: coefficient
    __shared__ float hvec[DHID];
    int bp = blockIdx.x;
    int hh = bp >> 8, b = (bp >> 5) & 7, blk = bp & 31;
    int ph = (b << 2) | hh;
    int tid = threadIdx.x;
    if (tid < NK) {
        int p = blk * NK + tid;
        node_s[tid] = order[ph * NN + p];
        val_s[tid]  = val[ph * NN + p];
        tgt_s[tid]  = tgt[ph * NN + p];
        rcnt[tid] = 0; rfill[tid] = 0;
    }
    __syncthreads();
    int e0 = bp * CAP_BP;
    int ne = min(fill[bp], CAP_BP);
    for (int t = tid; t < ne; t += 256)
        atomicAdd(&rcnt[tgt_s[elist[e0 + t] & 0xffff]], 1);
    __syncthreads();
    if (tid < NK) rend[tid] = rcnt[tid];
    __syncthreads();
    for (int off = 1; off < NK; off <<= 1) {
        int v = 0;
        if (tid < NK && tid >= off) v = rend[tid - off];
        __syncthreads();
        if (tid < NK) rend[tid] += v;
        __syncthreads();
    }
    for (int t = tid; t < ne; t += 256) {
        unsigned ent = elist[e0 + t];
        int ss = ent & 0xffff, sd = ent >> 16;
        int row = tgt_s[ss];
        int slot = atomicAdd(&rfill[row], 1);
        int p0 = rend[row] - rcnt[row] + slot;
        es_node[p0] = node_s[sd];
        es_coef[p0] = val_s[ss] * val_s[sd] * val_s[sd];
    }
    __syncthreads();
    float hsum = 0.f;
    for (int r = 0; r < NK; ++r) {
        int n = rcnt[r];
        if (n == 0) continue;                 // ~60% of rows empty: relu(0)=0
        int s0 = rend[r] - n;
        float m = 0.f;
        for (int i = 0; i < n; ++i)
            m = fmaf(es_coef[s0 + i],
                     G[((size_t)(b * NN + es_node[s0 + i])) * DHID + tid], m);
        hsum += fmaxf(m, 0.f);
    }
    hvec[tid] = hsum * (1.0f / NK);
    __syncthreads();
    if (tid < NCLS) {
        float s = 0.f;
        for (int q = 0; q < DHID; ++q) s = fmaf(hvec[q], Wo[q * NCLS + tid], s);
        logits_bp[bp * NCLS + tid] = s;
    }
}

// head-mean + log_softmax -> (8,32,16)
__global__ void k10_final(const float* __restrict__ logits_bp, float* __restrict__ out) {
    int t = threadIdx.x;                 // 256 = 8*32
    int b = t >> 5, blk = t & 31;
    float v[NCLS];
#pragma unroll
    for (int c = 0; c < NCLS; ++c) {
        float s = 0.f;
        for (int hh = 0; hh < NH; ++hh)
            s += logits_bp[(((hh * NB + b) * NJ) + blk) * NCLS + c];
        v[c] = s * 0.25f;
    }
    float mx = v[0];
#pragma unroll
    for (int c = 1; c < NCLS; ++c) mx = fmaxf(mx, v[c]);
    float se = 0.f;
#pragma unroll
    for (int c = 0; c < NCLS; ++c) se += expf(v[c] - mx);
    float lse = logf(se);
#pragma unroll
    for (int c = 0; c < NCLS; ++c) out[t * NCLS + c] = v[c] - mx - lse;
}

extern "C" void kernel_launch(void* const* d_in, const int* in_sizes, int n_in,
                              void* d_out, int out_size, void* d_ws, size_t ws_size,
                              hipStream_t stream) {
    const float* x  = (const float*)d_in[0];
    const float* wr = (const float*)d_in[1];
    const float* W1 = (const float*)d_in[2];
    const float* Wo = (const float*)d_in[3];
    const int*   ei = (const int*)d_in[4];

    char* ws = (char*)d_ws;
    int*      deg_i      = (int*)(ws + 0);          // 128 KB
    float*    rdeg       = (float*)(ws + 131072);   // 128 KB
    float*    scores_pre = (float*)(ws + 262144);   // 512 KB
    int*      iscore     = (int*)(ws + 786432);     // 512 KB
    float*    xapp       = (float*)(ws + 1310720);  // 16 MB
    float*    G          = (float*)(ws + 18087936); // 32 MB
    int*      order      = (int*)(ws + 51642368);   // 512 KB
    int*      pos        = (int*)(ws + 52166656);
    int*      tgt        = (int*)(ws + 52690944);
    float*    val        = (float*)(ws + 53215232);
    int*      fill       = (int*)(ws + 53743616);   // 4 KB (per-bpid count)
    int*      csr_src    = (int*)(ws + 53755904);   // 2 MB (lifetime ends at k4)
    unsigned short* w1t  = (unsigned short*)(ws + 55853056); // 128 KB (dead before elist writes)
    unsigned* elist      = (unsigned*)(ws + 53755904); // 2 MB (aliases csr_src; written at k6_bin)
    float*    logits_bp  = (float*)(ws + 62144512); // 64 KB
    int*      nbase      = (int*)(ws + 62210048);   // 128 KB + 4
    int*      fill2      = (int*)(ws + 62341184);   // 128 KB
    unsigned long long* sorted64 = (unsigned long long*)(ws + 9699328); // 1 MB (inside xapp, dead after kg_mfma)

    k0_init<<<512, 256, 0, stream>>>(deg_i, iscore, fill, fill2);
    k1_deg<<<2048, 256, 0, stream>>>(ei, deg_i);
    k1b_rdeg<<<128, 256, 0, stream>>>(deg_i, rdeg);
    kw_w1t<<<256, 256, 0, stream>>>(W1, w1t);
    k2_scores<<<512, 256, 0, stream>>>(x, wr, scores_pre);
    k3_scatter_scores<<<8192, 256, 0, stream>>>(ei, rdeg, scores_pre, iscore);
    k3b_scan<<<1, 1024, 0, stream>>>(deg_i, nbase);
    k3c_fill_csr<<<2048, 256, 0, stream>>>(ei, nbase, fill2, csr_src);
    k4_gather<<<8192, 256, 0, stream>>>(csr_src, nbase, rdeg, x, xapp);
    kg_mfma<<<512, 256, 0, stream>>>(x, xapp, w1t, G);        // last consumer of xapp
    k5a_chunk<<<256, 256, 0, stream>>>(scores_pre, iscore, deg_i, sorted64);
    k5b_rank<<<512, 256, 0, stream>>>(sorted64, order, pos, val);
    k5c_tgt<<<1024, 128, 0, stream>>>(order, tgt);
    k6_bin<<<256, 256, 0, stream>>>(ei, pos, fill, elist);    // elist overwrites csr_src (dead)
    k9_block<<<BPB, 256, 0, stream>>>(G, order, val, tgt, fill, elist, Wo, logits_bp);
    k10_final<<<1, 256, 0, stream>>>(logits_bp, (float*)d_out);
}

// Round 8
// 241.045 us; speedup vs baseline: 1.9083x; 1.1382x over previous
//
#include <hip/hip_runtime.h>
#include <cmath>

#define NB 8
#define NN 4096
#define DF 128
#define NH 4
#define NJ 32
#define NK 128
#define NTOT (NB*NN)          // 32768
#define ETOT 524288           // 8 * 4096 * 16
#define BPB (NH*NB*NJ)        // 1024
#define DHID 256
#define NCLS 16
#define CAP_PB 96             // per (part, blk) LDS bucket capacity (avg ~8)
#define CAP_BP 512            // per-bpid elist segment capacity (avg ~64)

#define FP_SCALE 4194304.0    // 2^22 fixed-point for deterministic score accumulation
#define FP_INV   (1.0/4194304.0)

typedef short bf16x8 __attribute__((ext_vector_type(8)));
typedef float f32x4  __attribute__((ext_vector_type(4)));

__device__ __forceinline__ unsigned short f2bf(float f) {
    unsigned u = __float_as_uint(f);
    unsigned r = (u + 0x7FFFu + ((u >> 16) & 1u)) >> 16;   // RNE
    return (unsigned short)r;
}

// sortable u64 key: ascending k64 == (descending score, ascending idx) — matches argsort(-s) stable
__device__ __forceinline__ unsigned long long make_key(float sc, int p) {
    unsigned u = __float_as_uint(sc);
    unsigned s = u ^ ((unsigned)((int)u >> 31) | 0x80000000u);   // ascending-float map
    return ((unsigned long long)(s ^ 0xFFFFFFFFu) << 12) | (unsigned)p;
}

// ---------------- init ----------------
__global__ void k0_init(int* deg_i, int* fill, int* fill2) {
    int t = blockIdx.x * blockDim.x + threadIdx.x;
    if (t < NTOT) { deg_i[t] = 0; fill2[t] = 0; }
    if (t < BPB) fill[t] = 0;
}

// in-degree (int, exact, deterministic)
__global__ void k1_deg(const int* __restrict__ ei, int* deg_i) {
    int e = blockIdx.x * blockDim.x + threadIdx.x;
    if (e >= ETOT) return;
    atomicAdd(&deg_i[ei[ETOT + e]], 1);
}

// rdeg = 1/sqrt(1+indeg)
__global__ void k1b_rdeg(const int* __restrict__ deg_i, float* __restrict__ rdeg) {
    int t = blockIdx.x * blockDim.x + threadIdx.x;
    if (t >= NTOT) return;
    rdeg[t] = 1.0f / sqrtf((float)(1 + deg_i[t]));
}

// W1T_bf[n][k] = bf16(W1[k][n])   (256x256, coalesced reads)
__global__ void kw_w1t(const float* __restrict__ W1, unsigned short* __restrict__ w1t) {
    int t = blockIdx.x * 256 + threadIdx.x;     // 65536
    int k = t >> 8, n = t & 255;
    w1t[n * 256 + k] = f2bf(W1[k * DHID + n]);
}

// scores_pre = x_flat @ W_rank  (double accum: minimizes sort-flip risk)
__global__ void k2_scores(const float* __restrict__ x, const float* __restrict__ wr,
                          float* __restrict__ scores_pre) {
    int t = blockIdx.x * blockDim.x + threadIdx.x;
    if (t >= NTOT * NH) return;
    int g = t >> 2, hh = t & 3;
    const float* xr = x + (size_t)g * DF;
    double acc = 0.0;
    for (int d0 = 0; d0 < DF; ++d0) acc += (double)xr[d0] * (double)wr[d0 * NH + hh];
    scores_pre[t] = (float)acc;
}

// exclusive scan of in-degrees over 32768 nodes (single block)
__global__ __launch_bounds__(1024) void k3b_scan(const int* __restrict__ deg_i, int* nbase) {
    __shared__ int part[1024];
    int t = threadIdx.x;
    int base0 = t * 32;
    int local[32];
    int s = 0;
#pragma unroll
    for (int i = 0; i < 32; ++i) { local[i] = s; s += deg_i[base0 + i]; }
    part[t] = s;
    __syncthreads();
    for (int off = 1; off < 1024; off <<= 1) {
        int v = (t >= off) ? part[t - off] : 0;
        __syncthreads();
        part[t] += v;
        __syncthreads();
    }
    int myoff = (t == 0) ? 0 : part[t - 1];
#pragma unroll
    for (int i = 0; i < 32; ++i) nbase[base0 + i] = myoff + local[i];
    if (t == 1023) nbase[NTOT] = part[1023];
}

// fill dst-CSR: csr_src[nbase[d] + slot] = s
__global__ void k3c_fill_csr(const int* __restrict__ ei, const int* __restrict__ nbase,
                             int* fill2, int* __restrict__ csr_src) {
    int e = blockIdx.x * blockDim.x + threadIdx.x;
    if (e >= ETOT) return;
    int s = ei[e], d = ei[ETOT + e];
    int slot = atomicAdd(&fill2[d], 1);
    csr_src[nbase[d] + slot] = s;
}

// score aggregation as GATHER with per-edge int quantization: identical per-edge ints
// to the old atomic scatter, int sum is order-independent -> bit-identical, deterministic.
__global__ void k3g_gather_scores(const int* __restrict__ csr_src, const int* __restrict__ nbase,
                                  const float* __restrict__ rdeg,
                                  const float* __restrict__ scores_pre,
                                  int* __restrict__ iscore) {
    int t = blockIdx.x * blockDim.x + threadIdx.x;   // 131072 = node*4 + hh
    if (t >= NTOT * NH) return;
    int d = t >> 2, hh = t & 3;
    float rdd = rdeg[d];
    int t0 = nbase[d], t1 = nbase[d + 1];
    int acc = 0;
    for (int e = t0; e < t1; ++e) {
        int s = csr_src[e];
        float w = rdeg[s] * rdd;
        double term = (double)(w * scores_pre[s * NH + hh]);
        acc += __double2int_rn(term * FP_SCALE);
    }
    iscore[t] = acc;
}

// gather: xapp[g,:] = x[g,:]/deg + sum_{s in N(g)} rdeg[g]*rdeg[s]*x[s,:]
// XCD-swizzled: batch b's nodes -> XCD b, so each XCD's 2 MB x-slice is L2-resident.
__global__ __launch_bounds__(256) void k4_gather(const int* __restrict__ csr_src,
                                                 const int* __restrict__ nbase,
                                                 const float* __restrict__ rdeg,
                                                 const float* __restrict__ x,
                                                 float* __restrict__ xapp) {
    int bid = blockIdx.x;                              // 8192
    int swz = (bid & 7) * 1024 + (bid >> 3);           // batch = bid & 7
    int wv = swz * 4 + (threadIdx.x >> 6);             // node id
    int lane = threadIdx.x & 63;
    float rd = rdeg[wv];
    const float2* xr = (const float2*)(x + (size_t)wv * DF);
    float2 v = xr[lane];
    float acc0 = v.x * rd * rd, acc1 = v.y * rd * rd;  // diagonal x/deg
    int t0 = nbase[wv], t1 = nbase[wv + 1];
    for (int t = t0; t < t1; ++t) {
        int s = csr_src[t];
        float w = rd * rdeg[s];
        float2 u = ((const float2*)(x + (size_t)s * DF))[lane];
        acc0 = fmaf(w, u.x, acc0);
        acc1 = fmaf(w, u.y, acc1);
    }
    ((float2*)(xapp + (size_t)wv * DF))[lane] = float2{acc0, acc1};
}

// G = concat(x, xapp) @ W1 via bf16 MFMA.  M=32768, N=256, K=256.
__global__ __launch_bounds__(256) void kg_mfma(const float* __restrict__ x,
                                               const float* __restrict__ xapp,
                                               const unsigned short* __restrict__ w1t,
                                               float* __restrict__ G) {
    __shared__ __align__(16) unsigned short As[128 * 64];  // [row][k] swizzled
    __shared__ __align__(16) unsigned short Bs[128 * 64];  // [n][k]   swizzled
    int bid = blockIdx.x;
    int m0 = (bid >> 1) * 128, n0 = (bid & 1) * 128;
    int tid = threadIdx.x, lane = tid & 63, wid = tid >> 6;
    int wr = wid >> 1, wc = wid & 1;
    f32x4 acc[4][4];
#pragma unroll
    for (int mi = 0; mi < 4; ++mi)
#pragma unroll
        for (int ni = 0; ni < 4; ++ni) acc[mi][ni] = f32x4{0.f, 0.f, 0.f, 0.f};

    for (int kk = 0; kk < 4; ++kk) {
        int k0 = kk * 64;
        const float* Asrc = (k0 < 128) ? x : xapp;
        int kbase = k0 & 127;
#pragma unroll
        for (int i = 0; i < 4; ++i) {
            int gi = tid + i * 256;
            int r = gi >> 3, c = gi & 7;
            int csrc = c ^ (r & 7);
            const float* sp = Asrc + (size_t)(m0 + r) * DF + kbase + csrc * 8;
            float4 lo = *(const float4*)sp;
            float4 hi = *(const float4*)(sp + 4);
            unsigned short u[8] = {f2bf(lo.x), f2bf(lo.y), f2bf(lo.z), f2bf(lo.w),
                                   f2bf(hi.x), f2bf(hi.y), f2bf(hi.z), f2bf(hi.w)};
            *(bf16x8*)&As[r * 64 + c * 8] = *(bf16x8*)u;
        }
#pragma unroll
        for (int i = 0; i < 4; ++i) {
            int gi = tid + i * 256;
            int r = gi >> 3, c = gi & 7;
            int csrc = c ^ (r & 7);
            *(bf16x8*)&Bs[r * 64 + c * 8] =
                *(const bf16x8*)(w1t + (size_t)(n0 + r) * 256 + k0 + csrc * 8);
        }
        __syncthreads();
#pragma unroll
        for (int ks = 0; ks < 2; ++ks) {
            bf16x8 af[4], bfr[4];
#pragma unroll
            for (int mi = 0; mi < 4; ++mi) {
                int r = wr * 64 + mi * 16 + (lane & 15);
                int gl = ks * 4 + (lane >> 4);
                af[mi] = *(const bf16x8*)&As[r * 64 + (gl ^ (r & 7)) * 8];
            }
#pragma unroll
            for (int ni = 0; ni < 4; ++ni) {
                int r = wc * 64 + ni * 16 + (lane & 15);
                int gl = ks * 4 + (lane >> 4);
                bfr[ni] = *(const bf16x8*)&Bs[r * 64 + (gl ^ (r & 7)) * 8];
            }
#pragma unroll
            for (int mi = 0; mi < 4; ++mi)
#pragma unroll
                for (int ni = 0; ni < 4; ++ni)
                    acc[mi][ni] = __builtin_amdgcn_mfma_f32_16x16x32_bf16(
                        af[mi], bfr[ni], acc[mi][ni], 0, 0, 0);
        }
        __syncthreads();
    }
#pragma unroll
    for (int mi = 0; mi < 4; ++mi) {
        int rbase = m0 + wr * 64 + mi * 16 + (lane >> 4) * 4;
#pragma unroll
        for (int ni = 0; ni < 4; ++ni) {
            int col = n0 + wc * 64 + ni * 16 + (lane & 15);
#pragma unroll
            for (int j = 0; j < 4; ++j)
                G[(size_t)(rbase + j) * DHID + col] = acc[mi][ni][j];
        }
    }
}

// sort phase A: 512-element chunk bitonic sort on packed u64 keys (one block per chunk)
__global__ __launch_bounds__(256) void k5a_chunk(const float* __restrict__ scores_pre,
                                                 const int* __restrict__ iscore,
                                                 const int* __restrict__ deg_i,
                                                 unsigned long long* __restrict__ sorted64) {
    __shared__ unsigned long long sk[512];
    int blk = blockIdx.x;            // seg*8 + chunk
    int seg = blk >> 3, chunk = blk & 7;
    int b = seg >> 2, hh = seg & 3;
    int tid = threadIdx.x;
    for (int i = tid; i < 512; i += 256) {
        int p = chunk * 512 + i;
        int g = b * NN + p;
        float dg = (float)(1 + deg_i[g]);
        float sc = scores_pre[g * NH + hh] / dg + (float)((double)iscore[g * NH + hh] * FP_INV);
        sk[i] = make_key(sc, p);
    }
    __syncthreads();
    for (int size = 2; size <= 512; size <<= 1) {
        for (int stride = size >> 1; stride > 0; stride >>= 1) {
            for (int p = tid; p < 512; p += 256) {
                int q = p ^ stride;
                if (q > p) {
                    unsigned long long kp = sk[p], kq = sk[q];
                    bool before_qp = (kq < kp);
                    bool asc = ((p & size) == 0);
                    if (asc ? before_qp : !before_qp) { sk[p] = kq; sk[q] = kp; }
                }
            }
            __syncthreads();
        }
    }
    for (int i = tid; i < 512; i += 256)
        sorted64[seg * NN + chunk * 512 + i] = sk[i];
}

// sort phase B: rank via binary searches over the other 7 sorted chunks (no barriers)
__global__ __launch_bounds__(256) void k5b_rank(const unsigned long long* __restrict__ sorted64,
                                                int* __restrict__ order, int* __restrict__ pos,
                                                float* __restrict__ val) {
    int t = blockIdx.x * 256 + threadIdx.x;      // 131072
    int seg = t >> 12, i = t & 4095;
    int chunk = i >> 9, slot = i & 511;
    const unsigned long long* segp = sorted64 + (size_t)seg * NN;
    unsigned long long k = segp[chunk * 512 + slot];
    int rank = slot;
#pragma unroll
    for (int c = 0; c < 8; ++c) {
        if (c == chunk) continue;
        const unsigned long long* cp = segp + c * 512;
        int lo = 0, hi = 512;
        while (lo < hi) { int mid = (lo + hi) >> 1; lo = (cp[mid] < k) ? mid + 1 : lo; hi = (cp[mid] < k) ? hi : mid; }
        rank += lo;
    }
    int p = (int)(k & 4095u);
    pos[seg * NN + p] = rank;
    order[seg * NN + rank] = p;
    unsigned s = (unsigned)(k >> 12) ^ 0xFFFFFFFFu;
    unsigned u = s ^ (((int)s >= 0) ? 0xFFFFFFFFu : 0x80000000u);
    float sc = __uint_as_float(u);
    val[seg * NN + rank] = 1.0f / (1.0f + expf(-sc));
}

// sort phase C: tgt = rank of order[p] by node-id within its 128-block
__global__ __launch_bounds__(128) void k5c_tgt(const int* __restrict__ order,
                                               int* __restrict__ tgt) {
    __shared__ int o[128];
    int base = blockIdx.x * 128;     // = seg*4096 + j*128
    int tid = threadIdx.x;
    o[tid] = order[base + tid];
    __syncthreads();
    int me = o[tid];
    int r = 0;
#pragma unroll 16
    for (int s2 = 0; s2 < 128; ++s2) r += (o[s2] < me) ? 1 : 0;
    tgt[base + tid] = r;
}

// bin kept edges by block-pair id: LDS-staged pos row, LDS buckets, block-aggregated
// global atomics (one per nonzero bucket).
__global__ __launch_bounds__(256) void k6_bin(const int* __restrict__ ei,
                                              const int* __restrict__ pos,
                                              int* fill, unsigned* __restrict__ elist) {
    __shared__ unsigned short pos_l[NN];      // 8 KB (pos values < 4096)
    __shared__ unsigned buf[NJ][CAP_PB];      // 12 KB
    __shared__ int lcnt[NJ];
    __shared__ int gbase[NJ];
    int blkid = blockIdx.x;        // ph*8 + part
    int ph = blkid >> 3, part = blkid & 7;
    int b = ph >> 2, hh = ph & 3;
    int tid = threadIdx.x;
    for (int i = tid; i < NN; i += 256) pos_l[i] = (unsigned short)pos[ph * NN + i];
    if (tid < NJ) lcnt[tid] = 0;
    __syncthreads();
    int ebase = b * 65536 + part * 8192;
    for (int i = tid; i < 8192; i += 256) {
        int e = ebase + i;
        int s = ei[e], d = ei[ETOT + e];
        int ps = pos_l[s & 4095], pd = pos_l[d & 4095];
        if ((ps >> 7) == (pd >> 7)) {
            int blk = ps >> 7;
            int slot = atomicAdd(&lcnt[blk], 1);
            if (slot < CAP_PB)
                buf[blk][slot] = (unsigned)((ps & 127) | ((pd & 127) << 16));
        }
    }
    __syncthreads();
    if (tid < NJ) {
        int n = min(lcnt[tid], CAP_PB);
        lcnt[tid] = n;
        gbase[tid] = atomicAdd(&fill[((hh * NB + b) * NJ) + tid], n);
    }
    __syncthreads();
    for (int t = tid; t < NJ * CAP_PB; t += 256) {
        int blk = t / CAP_PB, i = t % CAP_PB;
        if (i < lcnt[blk]) {
            int g0 = gbase[blk] + i;
            if (g0 < CAP_BP) {
                int bpid = ((hh * NB + b) * NJ) + blk;
                elist[bpid * CAP_BP + g0] = buf[blk][i];
            }
        }
    }
}

// per-block: group kept edges by output row, then column-parallel register accumulation.
// XCD-swizzled so batch b's G-slice (4 MB) stays in one XCD's L2.
__global__ __launch_bounds__(256) void k9_block(const float* __restrict__ G,
                                                const int* __restrict__ order,
                                                const float* __restrict__ val,
                                                const int* __restrict__ tgt,
                                                const int* __restrict__ fill,
                                                const unsigned* __restrict__ elist,
                                                const float* __restrict__ Wo,
                                                float* __restrict__ logits_bp) {
    __shared__ float val_s[NK];
    __shared__ int   node_s[NK];
    __shared__ int   tgt_s[NK];
    __shared__ int   rcnt[NK];
    __shared__ int   rend[NK];
    __shared__ int   rfill[NK];
    __shared__ int   es_node[CAP_BP];
    __shared__ float es_coef[CAP_BP];
    __shared__ float hvec[DHID];
    int i0 = blockIdx.x;
    int xcd = i0 & 7, r0 = i0 >> 3;            // r0 in [0,128)
    int hh = r0 >> 5, blk = r0 & 31, b = xcd;  // batch -> XCD
    int bp = (hh * NB + b) * NJ + blk;
    int ph = (b << 2) | hh;
    int tid = threadIdx.x;
    if (tid < NK) {
        int p = blk * NK + tid;
        node_s[tid] = order[ph * NN + p];
        val_s[tid]  = val[ph * NN + p];
        tgt_s[tid]  = tgt[ph * NN + p];
        rcnt[tid] = 0; rfill[tid] = 0;
    }
    __syncthreads();
    int e0 = bp * CAP_BP;
    int ne = min(fill[bp], CAP_BP);
    for (int t = tid; t < ne; t += 256)
        atomicAdd(&rcnt[tgt_s[elist[e0 + t] & 0xffff]], 1);
    __syncthreads();
    if (tid < NK) rend[tid] = rcnt[tid];
    __syncthreads();
    for (int off = 1; off < NK; off <<= 1) {
        int v = 0;
        if (tid < NK && tid >= off) v = rend[tid - off];
        __syncthreads();
        if (tid < NK) rend[tid] += v;
        __syncthreads();
    }
    for (int t = tid; t < ne; t += 256) {
        unsigned ent = elist[e0 + t];
        int ss = ent & 0xffff, sd = ent >> 16;
        int row = tgt_s[ss];
        int slot = atomicAdd(&rfill[row], 1);
        int p0 = rend[row] - rcnt[row] + slot;
        es_node[p0] = node_s[sd];
        es_coef[p0] = val_s[ss] * val_s[sd] * val_s[sd];
    }
    __syncthreads();
    float hsum = 0.f;
    for (int r = 0; r < NK; ++r) {
        int n = rcnt[r];
        if (n == 0) continue;
        int s0 = rend[r] - n;
        float m = 0.f;
        for (int i = 0; i < n; ++i)
            m = fmaf(es_coef[s0 + i],
                     G[((size_t)(b * NN + es_node[s0 + i])) * DHID + tid], m);
        hsum += fmaxf(m, 0.f);
    }
    hvec[tid] = hsum * (1.0f / NK);
    __syncthreads();
    if (tid < NCLS) {
        float s = 0.f;
        for (int q = 0; q < DHID; ++q) s = fmaf(hvec[q], Wo[q * NCLS + tid], s);
        logits_bp[bp * NCLS + tid] = s;
    }
}

// head-mean + log_softmax -> (8,32,16)
__global__ void k10_final(const float* __restrict__ logits_bp, float* __restrict__ out) {
    int t = threadIdx.x;                 // 256 = 8*32
    int b = t >> 5, blk = t & 31;
    float v[NCLS];
#pragma unroll
    for (int c = 0; c < NCLS; ++c) {
        float s = 0.f;
        for (int hh = 0; hh < NH; ++hh)
            s += logits_bp[(((hh * NB + b) * NJ) + blk) * NCLS + c];
        v[c] = s * 0.25f;
    }
    float mx = v[0];
#pragma unroll
    for (int c = 1; c < NCLS; ++c) mx = fmaxf(mx, v[c]);
    float se = 0.f;
#pragma unroll
    for (int c = 0; c < NCLS; ++c) se += expf(v[c] - mx);
    float lse = logf(se);
#pragma unroll
    for (int c = 0; c < NCLS; ++c) out[t * NCLS + c] = v[c] - mx - lse;
}

extern "C" void kernel_launch(void* const* d_in, const int* in_sizes, int n_in,
                              void* d_out, int out_size, void* d_ws, size_t ws_size,
                              hipStream_t stream) {
    const float* x  = (const float*)d_in[0];
    const float* wr = (const float*)d_in[1];
    const float* W1 = (const float*)d_in[2];
    const float* Wo = (const float*)d_in[3];
    const int*   ei = (const int*)d_in[4];

    char* ws = (char*)d_ws;
    int*      deg_i      = (int*)(ws + 0);          // 128 KB
    float*    rdeg       = (float*)(ws + 131072);   // 128 KB
    float*    scores_pre = (float*)(ws + 262144);   // 512 KB
    int*      iscore     = (int*)(ws + 786432);     // 512 KB
    float*    xapp       = (float*)(ws + 1310720);  // 16 MB
    float*    G          = (float*)(ws + 18087936); // 32 MB
    int*      order      = (int*)(ws + 51642368);   // 512 KB
    int*      pos        = (int*)(ws + 52166656);
    int*      tgt        = (int*)(ws + 52690944);
    float*    val        = (float*)(ws + 53215232);
    int*      fill       = (int*)(ws + 53743616);   // 4 KB (per-bpid count)
    int*      csr_src    = (int*)(ws + 53755904);   // 2 MB (lifetime ends at k4)
    unsigned short* w1t  = (unsigned short*)(ws + 55853056); // 128 KB
    unsigned* elist      = (unsigned*)(ws + 53755904); // 2 MB (aliases csr_src; written at k6_bin)
    float*    logits_bp  = (float*)(ws + 62144512); // 64 KB
    int*      nbase      = (int*)(ws + 62210048);   // 128 KB + 4
    int*      fill2      = (int*)(ws + 62341184);   // 128 KB
    unsigned long long* sorted64 = (unsigned long long*)(ws + 9699328); // 1 MB (inside xapp, dead after kg_mfma)

    k0_init<<<128, 256, 0, stream>>>(deg_i, fill, fill2);
    k1_deg<<<2048, 256, 0, stream>>>(ei, deg_i);
    k1b_rdeg<<<128, 256, 0, stream>>>(deg_i, rdeg);
    kw_w1t<<<256, 256, 0, stream>>>(W1, w1t);
    k2_scores<<<512, 256, 0, stream>>>(x, wr, scores_pre);
    k3b_scan<<<1, 1024, 0, stream>>>(deg_i, nbase);
    k3c_fill_csr<<<2048, 256, 0, stream>>>(ei, nbase, fill2, csr_src);
    k3g_gather_scores<<<512, 256, 0, stream>>>(csr_src, nbase, rdeg, scores_pre, iscore);
    k4_gather<<<8192, 256, 0, stream>>>(csr_src, nbase, rdeg, x, xapp);
    kg_mfma<<<512, 256, 0, stream>>>(x, xapp, w1t, G);        // last consumer of xapp
    k5a_chunk<<<256, 256, 0, stream>>>(scores_pre, iscore, deg_i, sorted64);
    k5b_rank<<<512, 256, 0, stream>>>(sorted64, order, pos, val);
    k5c_tgt<<<1024, 128, 0, stream>>>(order, tgt);
    k6_bin<<<256, 256, 0, stream>>>(ei, pos, fill, elist);    // elist overwrites csr_src (dead)
    k9_block<<<BPB, 256, 0, stream>>>(G, order, val, tgt, fill, elist, Wo, logits_bp);
    k10_final<<<1, 256, 0, stream>>>(logits_bp, (float*)d_out);
}

// Round 9
// 234.674 us; speedup vs baseline: 1.9601x; 1.0271x over previous
//
#include <hip/hip_runtime.h>
#include <cmath>

#define NB 8
#define NN 4096
#define DF 128
#define NH 4
#define NJ 32
#define NK 128
#define NTOT (NB*NN)          // 32768
#define ETOT 524288           // 8 * 4096 * 16
#define BPB (NH*NB*NJ)        // 1024
#define DHID 256
#define NCLS 16
#define CAP_PB 96             // per (part, blk) LDS bucket capacity (avg ~8)
#define CAP_BP 512            // per-bpid elist segment capacity (avg ~64)

#define FP_SCALE 4194304.0    // 2^22 fixed-point for deterministic score accumulation
#define FP_INV   (1.0/4194304.0)

typedef short bf16x8 __attribute__((ext_vector_type(8)));
typedef float f32x4  __attribute__((ext_vector_type(4)));

__device__ __forceinline__ unsigned short f2bf(float f) {
    unsigned u = __float_as_uint(f);
    unsigned r = (u + 0x7FFFu + ((u >> 16) & 1u)) >> 16;   // RNE
    return (unsigned short)r;
}

// sortable u64 key: ascending k64 == (descending score, ascending idx) — matches argsort(-s) stable
__device__ __forceinline__ unsigned long long make_key(float sc, int p) {
    unsigned u = __float_as_uint(sc);
    unsigned s = u ^ ((unsigned)((int)u >> 31) | 0x80000000u);   // ascending-float map
    return ((unsigned long long)(s ^ 0xFFFFFFFFu) << 12) | (unsigned)p;
}

// ---------------- init ----------------
__global__ void k0_init(int* deg_i, int* fill, int* fill2) {
    int t = blockIdx.x * blockDim.x + threadIdx.x;
    if (t < NTOT) { deg_i[t] = 0; fill2[t] = 0; }
    if (t < BPB) fill[t] = 0;
}

// in-degree (int, exact, deterministic)
__global__ void k1_deg(const int* __restrict__ ei, int* deg_i) {
    int e = blockIdx.x * blockDim.x + threadIdx.x;
    if (e >= ETOT) return;
    atomicAdd(&deg_i[ei[ETOT + e]], 1);
}

// fused prep: [0,2048) x->bf16 | [2048,2176) rdeg | [2176,2432) W1T bf16 | [2432,2944) scores
__global__ __launch_bounds__(256) void k_prep(const float* __restrict__ x,
                                              const float* __restrict__ W1,
                                              const float* __restrict__ wr,
                                              const int* __restrict__ deg_i,
                                              unsigned short* __restrict__ xbf,
                                              float* __restrict__ rdeg,
                                              unsigned short* __restrict__ w1t,
                                              float* __restrict__ scores_pre) {
    int bid = blockIdx.x, tid = threadIdx.x;
    if (bid < 2048) {                       // x -> bf16, 8 elems/thread
        int idx = bid * 256 + tid;
        const float* sp = x + (size_t)idx * 8;
        float4 lo = *(const float4*)sp;
        float4 hi = *(const float4*)(sp + 4);
        unsigned short u[8] = {f2bf(lo.x), f2bf(lo.y), f2bf(lo.z), f2bf(lo.w),
                               f2bf(hi.x), f2bf(hi.y), f2bf(hi.z), f2bf(hi.w)};
        *(bf16x8*)(xbf + (size_t)idx * 8) = *(bf16x8*)u;
    } else if (bid < 2176) {                // rdeg
        int t = (bid - 2048) * 256 + tid;
        rdeg[t] = 1.0f / sqrtf((float)(1 + deg_i[t]));
    } else if (bid < 2432) {                // W1T bf16
        int t = (bid - 2176) * 256 + tid;
        int k = t >> 8, n = t & 255;
        w1t[n * 256 + k] = f2bf(W1[k * DHID + n]);
    } else {                                // scores_pre = x @ W_rank (double accum)
        int t = (bid - 2432) * 256 + tid;
        int g = t >> 2, hh = t & 3;
        const float* xr = x + (size_t)g * DF;
        double acc = 0.0;
        for (int d0 = 0; d0 < DF; ++d0) acc += (double)xr[d0] * (double)wr[d0 * NH + hh];
        scores_pre[t] = (float)acc;
    }
}

// exclusive scan of in-degrees over 32768 nodes (single block)
__global__ __launch_bounds__(1024) void k3b_scan(const int* __restrict__ deg_i, int* nbase) {
    __shared__ int part[1024];
    int t = threadIdx.x;
    int base0 = t * 32;
    int local[32];
    int s = 0;
#pragma unroll
    for (int i = 0; i < 32; ++i) { local[i] = s; s += deg_i[base0 + i]; }
    part[t] = s;
    __syncthreads();
    for (int off = 1; off < 1024; off <<= 1) {
        int v = (t >= off) ? part[t - off] : 0;
        __syncthreads();
        part[t] += v;
        __syncthreads();
    }
    int myoff = (t == 0) ? 0 : part[t - 1];
#pragma unroll
    for (int i = 0; i < 32; ++i) nbase[base0 + i] = myoff + local[i];
    if (t == 1023) nbase[NTOT] = part[1023];
}

// fill dst-CSR: csr_src[nbase[d] + slot] = s
__global__ void k3c_fill_csr(const int* __restrict__ ei, const int* __restrict__ nbase,
                             int* fill2, int* __restrict__ csr_src) {
    int e = blockIdx.x * blockDim.x + threadIdx.x;
    if (e >= ETOT) return;
    int s = ei[e], d = ei[ETOT + e];
    int slot = atomicAdd(&fill2[d], 1);
    csr_src[nbase[d] + slot] = s;
}

// fused: [0,8192) xapp gather (XCD-swizzled, bf16 output) | [8192,8704) score gather.
// Score gather: per-edge int quantization identical to atomic-scatter version; int sum is
// order-independent -> bit-identical iscore, deterministic.
__global__ __launch_bounds__(256) void k4_gather(const int* __restrict__ csr_src,
                                                 const int* __restrict__ nbase,
                                                 const float* __restrict__ rdeg,
                                                 const float* __restrict__ x,
                                                 const float* __restrict__ scores_pre,
                                                 unsigned* __restrict__ xappbf,
                                                 int* __restrict__ iscore) {
    int bid = blockIdx.x;
    if (bid < 8192) {
        int swz = (bid & 7) * 1024 + (bid >> 3);           // batch = bid & 7 -> XCD
        int wv = swz * 4 + (threadIdx.x >> 6);             // node id
        int lane = threadIdx.x & 63;
        float rd = rdeg[wv];
        float2 v = ((const float2*)(x + (size_t)wv * DF))[lane];
        float acc0 = v.x * rd * rd, acc1 = v.y * rd * rd;  // diagonal x/deg
        int t0 = nbase[wv], t1 = nbase[wv + 1];
        for (int t = t0; t < t1; ++t) {
            int s = csr_src[t];
            float w = rd * rdeg[s];
            float2 u = ((const float2*)(x + (size_t)s * DF))[lane];
            acc0 = fmaf(w, u.x, acc0);
            acc1 = fmaf(w, u.y, acc1);
        }
        xappbf[(size_t)wv * 64 + lane] =
            (unsigned)f2bf(acc0) | ((unsigned)f2bf(acc1) << 16);
    } else {
        int t = (bid - 8192) * 256 + threadIdx.x;          // node*4 + hh
        int d = t >> 2, hh = t & 3;
        float rdd = rdeg[d];
        int t0 = nbase[d], t1 = nbase[d + 1];
        int acc = 0;
        for (int e = t0; e < t1; ++e) {
            int s = csr_src[e];
            float w = rdeg[s] * rdd;
            double term = (double)(w * scores_pre[s * NH + hh]);
            acc += __double2int_rn(term * FP_SCALE);
        }
        iscore[t] = acc;
    }
}

// G = concat(x, xapp)_bf16 @ W1 via bf16 MFMA.  M=32768, N=256, K=256.
// A/B staged as pure ushort8 copies (16B/lane), XOR-swizzled LDS.
__global__ __launch_bounds__(256) void kg_mfma(const unsigned short* __restrict__ xbf,
                                               const unsigned short* __restrict__ xappbf,
                                               const unsigned short* __restrict__ w1t,
                                               float* __restrict__ G) {
    __shared__ __align__(16) unsigned short As[128 * 64];  // [row][k] swizzled
    __shared__ __align__(16) unsigned short Bs[128 * 64];  // [n][k]   swizzled
    int bid = blockIdx.x;
    int m0 = (bid >> 1) * 128, n0 = (bid & 1) * 128;
    int tid = threadIdx.x, lane = tid & 63, wid = tid >> 6;
    int wr = wid >> 1, wc = wid & 1;
    f32x4 acc[4][4];
#pragma unroll
    for (int mi = 0; mi < 4; ++mi)
#pragma unroll
        for (int ni = 0; ni < 4; ++ni) acc[mi][ni] = f32x4{0.f, 0.f, 0.f, 0.f};

    for (int kk = 0; kk < 4; ++kk) {
        int k0 = kk * 64;
        const unsigned short* Asrc = (kk < 2) ? xbf : xappbf;
        int kbase = k0 & 127;
#pragma unroll
        for (int i = 0; i < 4; ++i) {
            int gi = tid + i * 256;
            int r = gi >> 3, c = gi & 7;
            int csrc = c ^ (r & 7);
            *(bf16x8*)&As[r * 64 + c * 8] =
                *(const bf16x8*)(Asrc + (size_t)(m0 + r) * DF + kbase + csrc * 8);
        }
#pragma unroll
        for (int i = 0; i < 4; ++i) {
            int gi = tid + i * 256;
            int r = gi >> 3, c = gi & 7;
            int csrc = c ^ (r & 7);
            *(bf16x8*)&Bs[r * 64 + c * 8] =
                *(const bf16x8*)(w1t + (size_t)(n0 + r) * 256 + k0 + csrc * 8);
        }
        __syncthreads();
#pragma unroll
        for (int ks = 0; ks < 2; ++ks) {
            bf16x8 af[4], bfr[4];
#pragma unroll
            for (int mi = 0; mi < 4; ++mi) {
                int r = wr * 64 + mi * 16 + (lane & 15);
                int gl = ks * 4 + (lane >> 4);
                af[mi] = *(const bf16x8*)&As[r * 64 + (gl ^ (r & 7)) * 8];
            }
#pragma unroll
            for (int ni = 0; ni < 4; ++ni) {
                int r = wc * 64 + ni * 16 + (lane & 15);
                int gl = ks * 4 + (lane >> 4);
                bfr[ni] = *(const bf16x8*)&Bs[r * 64 + (gl ^ (r & 7)) * 8];
            }
#pragma unroll
            for (int mi = 0; mi < 4; ++mi)
#pragma unroll
                for (int ni = 0; ni < 4; ++ni)
                    acc[mi][ni] = __builtin_amdgcn_mfma_f32_16x16x32_bf16(
                        af[mi], bfr[ni], acc[mi][ni], 0, 0, 0);
        }
        __syncthreads();
    }
#pragma unroll
    for (int mi = 0; mi < 4; ++mi) {
        int rbase = m0 + wr * 64 + mi * 16 + (lane >> 4) * 4;
#pragma unroll
        for (int ni = 0; ni < 4; ++ni) {
            int col = n0 + wc * 64 + ni * 16 + (lane & 15);
#pragma unroll
            for (int j = 0; j < 4; ++j)
                G[(size_t)(rbase + j) * DHID + col] = acc[mi][ni][j];
        }
    }
}

// sort phase A: 512-element chunk bitonic sort on packed u64 keys (one block per chunk)
__global__ __launch_bounds__(256) void k5a_chunk(const float* __restrict__ scores_pre,
                                                 const int* __restrict__ iscore,
                                                 const int* __restrict__ deg_i,
                                                 unsigned long long* __restrict__ sorted64) {
    __shared__ unsigned long long sk[512];
    int blk = blockIdx.x;            // seg*8 + chunk
    int seg = blk >> 3, chunk = blk & 7;
    int b = seg >> 2, hh = seg & 3;
    int tid = threadIdx.x;
    for (int i = tid; i < 512; i += 256) {
        int p = chunk * 512 + i;
        int g = b * NN + p;
        float dg = (float)(1 + deg_i[g]);
        float sc = scores_pre[g * NH + hh] / dg + (float)((double)iscore[g * NH + hh] * FP_INV);
        sk[i] = make_key(sc, p);
    }
    __syncthreads();
    for (int size = 2; size <= 512; size <<= 1) {
        for (int stride = size >> 1; stride > 0; stride >>= 1) {
            for (int p = tid; p < 512; p += 256) {
                int q = p ^ stride;
                if (q > p) {
                    unsigned long long kp = sk[p], kq = sk[q];
                    bool before_qp = (kq < kp);
                    bool asc = ((p & size) == 0);
                    if (asc ? before_qp : !before_qp) { sk[p] = kq; sk[q] = kp; }
                }
            }
            __syncthreads();
        }
    }
    for (int i = tid; i < 512; i += 256)
        sorted64[seg * NN + chunk * 512 + i] = sk[i];
}

// sort phase B: rank via binary searches over the other 7 sorted chunks (no barriers)
__global__ __launch_bounds__(256) void k5b_rank(const unsigned long long* __restrict__ sorted64,
                                                int* __restrict__ order, int* __restrict__ pos,
                                                float* __restrict__ val) {
    int t = blockIdx.x * 256 + threadIdx.x;      // 131072
    int seg = t >> 12, i = t & 4095;
    int chunk = i >> 9, slot = i & 511;
    const unsigned long long* segp = sorted64 + (size_t)seg * NN;
    unsigned long long k = segp[chunk * 512 + slot];
    int rank = slot;
#pragma unroll
    for (int c = 0; c < 8; ++c) {
        if (c == chunk) continue;
        const unsigned long long* cp = segp + c * 512;
        int lo = 0, hi = 512;
        while (lo < hi) { int mid = (lo + hi) >> 1; lo = (cp[mid] < k) ? mid + 1 : lo; hi = (cp[mid] < k) ? hi : mid; }
        rank += lo;
    }
    int p = (int)(k & 4095u);
    pos[seg * NN + p] = rank;
    order[seg * NN + rank] = p;
    unsigned s = (unsigned)(k >> 12) ^ 0xFFFFFFFFu;
    unsigned u = s ^ (((int)s >= 0) ? 0xFFFFFFFFu : 0x80000000u);
    float sc = __uint_as_float(u);
    val[seg * NN + rank] = 1.0f / (1.0f + expf(-sc));
}

// sort phase C: tgt = rank of order[p] by node-id within its 128-block
__global__ __launch_bounds__(128) void k5c_tgt(const int* __restrict__ order,
                                               int* __restrict__ tgt) {
    __shared__ int o[128];
    int base = blockIdx.x * 128;     // = seg*4096 + j*128
    int tid = threadIdx.x;
    o[tid] = order[base + tid];
    __syncthreads();
    int me = o[tid];
    int r = 0;
#pragma unroll 16
    for (int s2 = 0; s2 < 128; ++s2) r += (o[s2] < me) ? 1 : 0;
    tgt[base + tid] = r;
}

// bin kept edges by block-pair id: LDS-staged pos row, LDS buckets, block-aggregated
// global atomics (one per nonzero bucket).
__global__ __launch_bounds__(256) void k6_bin(const int* __restrict__ ei,
                                              const int* __restrict__ pos,
                                              int* fill, unsigned* __restrict__ elist) {
    __shared__ unsigned short pos_l[NN];      // 8 KB (pos values < 4096)
    __shared__ unsigned buf[NJ][CAP_PB];      // 12 KB
    __shared__ int lcnt[NJ];
    __shared__ int gbase[NJ];
    int blkid = blockIdx.x;        // ph*8 + part
    int ph = blkid >> 3, part = blkid & 7;
    int b = ph >> 2, hh = ph & 3;
    int tid = threadIdx.x;
    for (int i = tid; i < NN; i += 256) pos_l[i] = (unsigned short)pos[ph * NN + i];
    if (tid < NJ) lcnt[tid] = 0;
    __syncthreads();
    int ebase = b * 65536 + part * 8192;
    for (int i = tid; i < 8192; i += 256) {
        int e = ebase + i;
        int s = ei[e], d = ei[ETOT + e];
        int ps = pos_l[s & 4095], pd = pos_l[d & 4095];
        if ((ps >> 7) == (pd >> 7)) {
            int blk = ps >> 7;
            int slot = atomicAdd(&lcnt[blk], 1);
            if (slot < CAP_PB)
                buf[blk][slot] = (unsigned)((ps & 127) | ((pd & 127) << 16));
        }
    }
    __syncthreads();
    if (tid < NJ) {
        int n = min(lcnt[tid], CAP_PB);
        lcnt[tid] = n;
        gbase[tid] = atomicAdd(&fill[((hh * NB + b) * NJ) + tid], n);
    }
    __syncthreads();
    for (int t = tid; t < NJ * CAP_PB; t += 256) {
        int blk = t / CAP_PB, i = t % CAP_PB;
        if (i < lcnt[blk]) {
            int g0 = gbase[blk] + i;
            if (g0 < CAP_BP) {
                int bpid = ((hh * NB + b) * NJ) + blk;
                elist[bpid * CAP_BP + g0] = buf[blk][i];
            }
        }
    }
}

// per-block: group kept edges by output row, then column-parallel register accumulation.
// XCD-swizzled so batch b's G-slice (4 MB) stays in one XCD's L2.
__global__ __launch_bounds__(256) void k9_block(const float* __restrict__ G,
                                                const int* __restrict__ order,
                                                const float* __restrict__ val,
                                                const int* __restrict__ tgt,
                                                const int* __restrict__ fill,
                                                const unsigned* __restrict__ elist,
                                                const float* __restrict__ Wo,
                                                float* __restrict__ logits_bp) {
    __shared__ float val_s[NK];
    __shared__ int   node_s[NK];
    __shared__ int   tgt_s[NK];
    __shared__ int   rcnt[NK];
    __shared__ int   rend[NK];
    __shared__ int   rfill[NK];
    __shared__ int   es_node[CAP_BP];
    __shared__ float es_coef[CAP_BP];
    __shared__ float hvec[DHID];
    int i0 = blockIdx.x;
    int xcd = i0 & 7, r0 = i0 >> 3;            // r0 in [0,128)
    int hh = r0 >> 5, blk = r0 & 31, b = xcd;  // batch -> XCD
    int bp = (hh * NB + b) * NJ + blk;
    int ph = (b << 2) | hh;
    int tid = threadIdx.x;
    if (tid < NK) {
        int p = blk * NK + tid;
        node_s[tid] = order[ph * NN + p];
        val_s[tid]  = val[ph * NN + p];
        tgt_s[tid]  = tgt[ph * NN + p];
        rcnt[tid] = 0; rfill[tid] = 0;
    }
    __syncthreads();
    int e0 = bp * CAP_BP;
    int ne = min(fill[bp], CAP_BP);
    for (int t = tid; t < ne; t += 256)
        atomicAdd(&rcnt[tgt_s[elist[e0 + t] & 0xffff]], 1);
    __syncthreads();
    if (tid < NK) rend[tid] = rcnt[tid];
    __syncthreads();
    for (int off = 1; off < NK; off <<= 1) {
        int v = 0;
        if (tid < NK && tid >= off) v = rend[tid - off];
        __syncthreads();
        if (tid < NK) rend[tid] += v;
        __syncthreads();
    }
    for (int t = tid; t < ne; t += 256) {
        unsigned ent = elist[e0 + t];
        int ss = ent & 0xffff, sd = ent >> 16;
        int row = tgt_s[ss];
        int slot = atomicAdd(&rfill[row], 1);
        int p0 = rend[row] - rcnt[row] + slot;
        es_node[p0] = node_s[sd];
        es_coef[p0] = val_s[ss] * val_s[sd] * val_s[sd];
    }
    __syncthreads();
    float hsum = 0.f;
    for (int r = 0; r < NK; ++r) {
        int n = rcnt[r];
        if (n == 0) continue;
        int s0 = rend[r] - n;
        float m = 0.f;
        for (int i = 0; i < n; ++i)
            m = fmaf(es_coef[s0 + i],
                     G[((size_t)(b * NN + es_node[s0 + i])) * DHID + tid], m);
        hsum += fmaxf(m, 0.f);
    }
    hvec[tid] = hsum * (1.0f / NK);
    __syncthreads();
    if (tid < NCLS) {
        float s = 0.f;
        for (int q = 0; q < DHID; ++q) s = fmaf(hvec[q], Wo[q * NCLS + tid], s);
        logits_bp[bp * NCLS + tid] = s;
    }
}

// head-mean + log_softmax -> (8,32,16)
__global__ void k10_final(const float* __restrict__ logits_bp, float* __restrict__ out) {
    int t = threadIdx.x;                 // 256 = 8*32
    int b = t >> 5, blk = t & 31;
    float v[NCLS];
#pragma unroll
    for (int c = 0; c < NCLS; ++c) {
        float s = 0.f;
        for (int hh = 0; hh < NH; ++hh)
            s += logits_bp[(((hh * NB + b) * NJ) + blk) * NCLS + c];
        v[c] = s * 0.25f;
    }
    float mx = v[0];
#pragma unroll
    for (int c = 1; c < NCLS; ++c) mx = fmaxf(mx, v[c]);
    float se = 0.f;
#pragma unroll
    for (int c = 0; c < NCLS; ++c) se += expf(v[c] - mx);
    float lse = logf(se);
#pragma unroll
    for (int c = 0; c < NCLS; ++c) out[t * NCLS + c] = v[c] - mx - lse;
}

extern "C" void kernel_launch(void* const* d_in, const int* in_sizes, int n_in,
                              void* d_out, int out_size, void* d_ws, size_t ws_size,
                              hipStream_t stream) {
    const float* x  = (const float*)d_in[0];
    const float* wr = (const float*)d_in[1];
    const float* W1 = (const float*)d_in[2];
    const float* Wo = (const float*)d_in[3];
    const int*   ei = (const int*)d_in[4];

    char* ws = (char*)d_ws;
    int*      deg_i      = (int*)(ws + 0);          // 128 KB
    float*    rdeg       = (float*)(ws + 131072);   // 128 KB
    float*    scores_pre = (float*)(ws + 262144);   // 512 KB
    int*      iscore     = (int*)(ws + 786432);     // 512 KB
    unsigned short* xbf  = (unsigned short*)(ws + 1310720);   // 8 MB
    unsigned* xappbf     = (unsigned*)(ws + 9699328);         // 8 MB (u32-packed bf16 pairs)
    float*    G          = (float*)(ws + 18087936); // 32 MB
    int*      order      = (int*)(ws + 51642368);   // 512 KB
    int*      pos        = (int*)(ws + 52166656);
    int*      tgt        = (int*)(ws + 52690944);
    float*    val        = (float*)(ws + 53215232);
    int*      fill       = (int*)(ws + 53743616);   // 4 KB (per-bpid count)
    int*      csr_src    = (int*)(ws + 53755904);   // 2 MB (lifetime ends at k4)
    unsigned short* w1t  = (unsigned short*)(ws + 55853056); // 128 KB
    unsigned* elist      = (unsigned*)(ws + 53755904); // 2 MB (aliases csr_src; written at k6_bin)
    float*    logits_bp  = (float*)(ws + 62144512); // 64 KB
    int*      nbase      = (int*)(ws + 62210048);   // 128 KB + 4
    int*      fill2      = (int*)(ws + 62341184);   // 128 KB
    unsigned long long* sorted64 = (unsigned long long*)(ws + 62472256); // 1 MB

    k0_init<<<128, 256, 0, stream>>>(deg_i, fill, fill2);
    k1_deg<<<2048, 256, 0, stream>>>(ei, deg_i);
    k_prep<<<2944, 256, 0, stream>>>(x, W1, wr, deg_i, xbf, rdeg, w1t, scores_pre);
    k3b_scan<<<1, 1024, 0, stream>>>(deg_i, nbase);
    k3c_fill_csr<<<2048, 256, 0, stream>>>(ei, nbase, fill2, csr_src);
    k4_gather<<<8704, 256, 0, stream>>>(csr_src, nbase, rdeg, x, scores_pre, xappbf, iscore);
    kg_mfma<<<512, 256, 0, stream>>>(xbf, (const unsigned short*)xappbf, w1t, G);
    k5a_chunk<<<256, 256, 0, stream>>>(scores_pre, iscore, deg_i, sorted64);
    k5b_rank<<<512, 256, 0, stream>>>(sorted64, order, pos, val);
    k5c_tgt<<<1024, 128, 0, stream>>>(order, tgt);
    k6_bin<<<256, 256, 0, stream>>>(ei, pos, fill, elist);    // elist overwrites csr_src (dead)
    k9_block<<<BPB, 256, 0, stream>>>(G, order, val, tgt, fill, elist, Wo, logits_bp);
    k10_final<<<1, 256, 0, stream>>>(logits_bp, (float*)d_out);
}